// Round 1
// baseline (3907.454 us; speedup 1.0000x reference)
//
#include <hip/hip_runtime.h>
#include <float.h>

#define D_DIM 784
#define N_TRAIN 50000
#define B_TEST 2048
#define N_CLASSES 10
#define TOPK 5

#define BM 64
#define BN 64
#define BK 16
#define NCH 32         // n-range chunks
#define CHUNK 1600     // 25 tiles of 64; 32*1600 = 51200 >= 50000

// ---------------- Phase 0: row sums of x_train ----------------
__global__ __launch_bounds__(256)
void rowsum_kernel(const float* __restrict__ x, float* __restrict__ s) {
    int row = blockIdx.x * 4 + (threadIdx.x >> 6);
    int lane = threadIdx.x & 63;
    if (row >= N_TRAIN) return;
    const float* p = x + (size_t)row * D_DIM;
    float acc = 0.f;
    for (int i = lane; i < D_DIM; i += 64) acc += p[i];
    #pragma unroll
    for (int off = 32; off > 0; off >>= 1) acc += __shfl_down(acc, off, 64);
    if (lane == 0) s[row] = acc;
}

// branch-free sorted-insert of (cv,ci) into 5-deep list (val desc, idx asc)
#define INSERT5(tvarr, tiarr, CV, CI)                                   \
    {                                                                   \
        float _cv = (CV); int _ci = (CI);                               \
        _Pragma("unroll")                                               \
        for (int _s = 0; _s < TOPK; ++_s) {                             \
            bool _bet = (_cv > tvarr[_s]) ||                            \
                        (_cv == tvarr[_s] && _ci < tiarr[_s]);          \
            float _fv = _bet ? tvarr[_s] : _cv;                         \
            int   _fi = _bet ? tiarr[_s] : _ci;                         \
            tvarr[_s] = _bet ? _cv : tvarr[_s];                         \
            tiarr[_s] = _bet ? _ci : tiarr[_s];                         \
            _cv = _fv; _ci = _fi;                                       \
        }                                                               \
    }

// ---------------- Phase A: tiled score GEMM + per-chunk top-5 ----------------
__global__ __launch_bounds__(256)
void knn_phaseA(const float* __restrict__ xt, const float* __restrict__ xtr,
                const float* __restrict__ strain,
                float* __restrict__ cval, int* __restrict__ cidx) {
    __shared__ float As[BK][BM + 4];   // +4 keeps 16B align, breaks pow2 stride
    __shared__ float Bs[BK][BN + 4];
    __shared__ float lv[BM][16][TOPK];
    __shared__ int   li[BM][16][TOPK];

    const int tid = threadIdx.x;
    const int tx = tid & 15, ty = tid >> 4;
    const int b0 = blockIdx.x * BM;
    const int chunk = blockIdx.y;
    const int n_base = chunk * CHUNK;

    const int lrow = tid >> 2;        // 0..63
    const int lk4  = (tid & 3) * 4;   // 0,4,8,12

    float tv[4][TOPK]; int ti[4][TOPK];
    #pragma unroll
    for (int i = 0; i < 4; ++i)
        #pragma unroll
        for (int s = 0; s < TOPK; ++s) { tv[i][s] = -FLT_MAX; ti[i][s] = 0x7fffffff; }

    for (int nt = 0; nt < CHUNK; nt += BN) {
        const int n0 = n_base + nt;
        double accd[4][4];
        #pragma unroll
        for (int i = 0; i < 4; ++i)
            #pragma unroll
            for (int j = 0; j < 4; ++j) accd[i][j] = 0.0;

        for (int kt = 0; kt < D_DIM; kt += BK) {
            // stage A tile (x_test[b0..b0+63][kt..kt+15])
            float4 av = *(const float4*)(xt + (size_t)(b0 + lrow) * D_DIM + kt + lk4);
            As[lk4 + 0][lrow] = av.x;
            As[lk4 + 1][lrow] = av.y;
            As[lk4 + 2][lrow] = av.z;
            As[lk4 + 3][lrow] = av.w;
            // stage B tile (x_train[n0..n0+63][kt..kt+15]), zero-pad OOB rows
            int nr = n0 + lrow;
            float4 bv = make_float4(0.f, 0.f, 0.f, 0.f);
            if (nr < N_TRAIN)
                bv = *(const float4*)(xtr + (size_t)nr * D_DIM + kt + lk4);
            Bs[lk4 + 0][lrow] = bv.x;
            Bs[lk4 + 1][lrow] = bv.y;
            Bs[lk4 + 2][lrow] = bv.z;
            Bs[lk4 + 3][lrow] = bv.w;
            __syncthreads();

            float accf[4][4] = {{0.f}};
            #pragma unroll
            for (int k = 0; k < BK; ++k) {
                float a[4], b[4];
                #pragma unroll
                for (int i = 0; i < 4; ++i) a[i] = As[k][ty * 4 + i];
                #pragma unroll
                for (int j = 0; j < 4; ++j) b[j] = Bs[k][tx * 4 + j];
                #pragma unroll
                for (int i = 0; i < 4; ++i)
                    #pragma unroll
                    for (int j = 0; j < 4; ++j) accf[i][j] += a[i] * b[j];
            }
            // fold chunk partial into fp64 accumulator (keeps ranking exact
            // to ~1e-5 vs min 5th/6th-neighbor gap ~2e-4)
            #pragma unroll
            for (int i = 0; i < 4; ++i)
                #pragma unroll
                for (int j = 0; j < 4; ++j) accd[i][j] += (double)accf[i][j];
            __syncthreads();
        }

        // score + per-thread top-5 update
        #pragma unroll
        for (int j = 0; j < 4; ++j) {
            int n = n0 + tx * 4 + j;
            if (n < N_TRAIN) {
                float sn = strain[n];
                #pragma unroll
                for (int i = 0; i < 4; ++i) {
                    float sc = (float)(2.0 * accd[i][j] - (double)sn);
                    if (sc > tv[i][TOPK - 1] ||
                        (sc == tv[i][TOPK - 1] && n < ti[i][TOPK - 1])) {
                        INSERT5(tv[i], ti[i], sc, n);
                    }
                }
            }
        }
    }

    // merge 16 column-threads per row via LDS
    #pragma unroll
    for (int i = 0; i < 4; ++i)
        #pragma unroll
        for (int s = 0; s < TOPK; ++s) {
            lv[ty * 4 + i][tx][s] = tv[i][s];
            li[ty * 4 + i][tx][s] = ti[i][s];
        }
    __syncthreads();

    if (tid < BM) {
        float bv5[TOPK]; int bi5[TOPK];
        #pragma unroll
        for (int s = 0; s < TOPK; ++s) { bv5[s] = -FLT_MAX; bi5[s] = 0x7fffffff; }
        for (int t = 0; t < 16; ++t)
            #pragma unroll
            for (int s = 0; s < TOPK; ++s) {
                float cv = lv[tid][t][s]; int ci = li[tid][t][s];
                if (cv > bv5[TOPK - 1] || (cv == bv5[TOPK - 1] && ci < bi5[TOPK - 1])) {
                    INSERT5(bv5, bi5, cv, ci);
                }
            }
        size_t base = ((size_t)(b0 + tid) * NCH + chunk) * TOPK;
        #pragma unroll
        for (int s = 0; s < TOPK; ++s) { cval[base + s] = bv5[s]; cidx[base + s] = bi5[s]; }
    }
}

// ---------------- Phase B: merge chunks, gather labels, vote ----------------
__global__ __launch_bounds__(256)
void knn_phaseB(const float* __restrict__ cval, const int* __restrict__ cidx,
                const int* __restrict__ y, int* __restrict__ out) {
    int b = blockIdx.x * blockDim.x + threadIdx.x;
    if (b >= B_TEST) return;
    const float* v = cval + (size_t)b * NCH * TOPK;
    const int* ix = cidx + (size_t)b * NCH * TOPK;
    float bv5[TOPK]; int bi5[TOPK];
    #pragma unroll
    for (int s = 0; s < TOPK; ++s) { bv5[s] = -FLT_MAX; bi5[s] = 0x7fffffff; }
    for (int t = 0; t < NCH * TOPK; ++t) {
        float cv = v[t]; int ci = ix[t];
        if (cv > bv5[TOPK - 1] || (cv == bv5[TOPK - 1] && ci < bi5[TOPK - 1])) {
            INSERT5(bv5, bi5, cv, ci);
        }
    }
    int lab[TOPK];
    #pragma unroll
    for (int s = 0; s < TOPK; ++s) lab[s] = y[bi5[s]];
    // argmax over class histogram; first (smallest) class wins ties
    int best_c = 0, best_cnt = -1;
    #pragma unroll
    for (int c = 0; c < N_CLASSES; ++c) {
        int cnt = 0;
        #pragma unroll
        for (int s = 0; s < TOPK; ++s) cnt += (lab[s] == c) ? 1 : 0;
        if (cnt > best_cnt) { best_cnt = cnt; best_c = c; }
    }
    out[b] = best_c;
}

extern "C" void kernel_launch(void* const* d_in, const int* in_sizes, int n_in,
                              void* d_out, int out_size, void* d_ws, size_t ws_size,
                              hipStream_t stream) {
    const float* x_test  = (const float*)d_in[0];   // [2048, 784]
    const float* x_train = (const float*)d_in[1];   // [50000, 784]
    const int*   y_train = (const int*)d_in[2];     // [50000] (int64 -> int32 by harness)
    // d_in[3] is k == 5 (hard-coded)
    int* out = (int*)d_out;                         // [2048] int32 labels

    // workspace layout (~2.8 MB)
    float* strain = (float*)d_ws;                          // 50000 floats
    float* cval   = strain + 50048;                        // 2048*32*5 floats
    int*   cidx   = (int*)(cval + (size_t)B_TEST * NCH * TOPK);

    rowsum_kernel<<<N_TRAIN / 4, 256, 0, stream>>>(x_train, strain);

    dim3 gridA(B_TEST / BM, NCH);
    knn_phaseA<<<gridA, 256, 0, stream>>>(x_test, x_train, strain, cval, cidx);

    knn_phaseB<<<(B_TEST + 255) / 256, 256, 0, stream>>>(cval, cidx, y_train, out);
}

// Round 2
// 1664.421 us; speedup vs baseline: 2.3476x; 2.3476x over previous
//
#include <hip/hip_runtime.h>
#include <float.h>
#include <stdint.h>

#define D_DIM 784
#define KPAD 800
#define N_TRAIN 50000
#define NPAD 50048
#define B_TEST 2048
#define N_CLASSES 10
#define TOPK 5
#define NBLK 391        // ceil(50048/128) n-blocks in fast path

typedef __attribute__((ext_vector_type(8))) _Float16 half8;
typedef __attribute__((ext_vector_type(4))) float float4v;

// branch-free sorted-insert of (cv,ci) into 5-deep list (val desc, idx asc)
#define INSERT5(tvarr, tiarr, CV, CI)                                   \
    {                                                                   \
        float _cv = (CV); int _ci = (CI);                               \
        _Pragma("unroll")                                               \
        for (int _s = 0; _s < TOPK; ++_s) {                             \
            bool _bet = (_cv > tvarr[_s]) ||                            \
                        (_cv == tvarr[_s] && _ci < tiarr[_s]);          \
            float _fv = _bet ? tvarr[_s] : _cv;                         \
            int   _fi = _bet ? tiarr[_s] : _ci;                         \
            tvarr[_s] = _bet ? _cv : tvarr[_s];                         \
            tiarr[_s] = _bet ? _ci : tiarr[_s];                         \
            _cv = _fv; _ci = _fi;                                       \
        }                                                               \
    }

// ---------------- rowsum of x_train (shared by both paths) ----------------
__global__ __launch_bounds__(256)
void rowsum_kernel(const float* __restrict__ x, float* __restrict__ s) {
    int row = blockIdx.x * 4 + (threadIdx.x >> 6);
    int lane = threadIdx.x & 63;
    if (row >= N_TRAIN) return;
    const float* p = x + (size_t)row * D_DIM;
    float acc = 0.f;
    for (int i = lane; i < D_DIM; i += 64) acc += p[i];
    #pragma unroll
    for (int off = 32; off > 0; off >>= 1) acc += __shfl_down(acc, off, 64);
    if (lane == 0) s[row] = acc;
}

// ---------------- fast path: split fp32 -> f16 hi/lo, padded ----------------
__global__ __launch_bounds__(256)
void split_f16(const float* __restrict__ src, _Float16* __restrict__ hi,
               _Float16* __restrict__ lo, int rows_src, long total_groups) {
    long idx = (long)blockIdx.x * 256 + threadIdx.x;   // one 8-elem group
    if (idx >= total_groups) return;
    int r = (int)(idx / 100);
    int g = (int)(idx % 100);
    float v[8];
    if (r < rows_src && g < 98) {
        const float* p = src + (size_t)r * D_DIM + g * 8;
        float4 a = *(const float4*)p;
        float4 b = *(const float4*)(p + 4);
        v[0]=a.x; v[1]=a.y; v[2]=a.z; v[3]=a.w;
        v[4]=b.x; v[5]=b.y; v[6]=b.z; v[7]=b.w;
    } else {
        #pragma unroll
        for (int i = 0; i < 8; ++i) v[i] = 0.f;
    }
    half8 h8, l8;
    #pragma unroll
    for (int i = 0; i < 8; ++i) {
        _Float16 h = (_Float16)v[i];
        h8[i] = h;
        l8[i] = (_Float16)(v[i] - (float)h);
    }
    size_t o = (size_t)r * KPAD + g * 8;
    *(half8*)(hi + o) = h8;
    *(half8*)(lo + o) = l8;
}

// ---------------- fast path: MFMA split-f16 GEMM + fused top-5 ----------------
__global__ __launch_bounds__(256, 3)
void knn_mfma(const _Float16* __restrict__ Ah, const _Float16* __restrict__ Al,
              const _Float16* __restrict__ Bh, const _Float16* __restrict__ Bl,
              const float* __restrict__ strain,
              float* __restrict__ cval, int* __restrict__ cidx) {
    __shared__ char lds_raw[45056] __attribute__((aligned(16)));
    _Float16* stage = (_Float16*)lds_raw;            // 4 tiles x 8192 B
    float* epi  = (float*)lds_raw;                   // [128 cols][68] floats
    float* lval = (float*)(lds_raw + 34816);         // [64][4][5]
    int*   lidx = (int*)(lds_raw + 34816 + 5120);    // [64][4][5]

    const int tid = threadIdx.x;
    const int w = tid >> 6, lane = tid & 63;
    const int l15 = lane & 15, q = lane >> 4;
    const int mb = blockIdx.y * 128;
    const int nb = blockIdx.x * 128;
    const int mw = (w & 1) * 64, nw = (w >> 1) * 64;

    // wave w stages one array: 0=Ah 1=Al 2=Bh 3=Bl
    const _Float16* srcs[4] = {Ah, Al, Bh, Bl};
    const _Float16* src = srcs[w];
    const int rowbase = (w < 2) ? mb : nb;
    const _Float16* srow = src + (size_t)rowbase * KPAD;
    _Float16* ldsw = stage + w * 4096;               // halves

    // per-chunk swizzled global offsets (halves): slot = c*64+lane
    int choff[8];
    #pragma unroll
    for (int c = 0; c < 8; ++c) {
        int slot = c * 64 + lane;
        int m = slot >> 2;
        int k8 = (slot & 3) ^ ((m >> 1) & 3);
        choff[c] = m * KPAD + k8 * 8;
    }
    // frag LDS offsets (halves): slot*8
    int aoff[4], boff[4];
    #pragma unroll
    for (int i = 0; i < 4; ++i) {
        int ma = mw + i * 16 + l15;
        aoff[i] = (4 * ma + (q ^ ((ma >> 1) & 3))) * 8;
        int nr = nw + i * 16 + l15;
        boff[i] = (4 * nr + (q ^ ((nr >> 1) & 3))) * 8;
    }

    const _Float16* sAh = stage;
    const _Float16* sAl = stage + 4096;
    const _Float16* sBh = stage + 8192;
    const _Float16* sBl = stage + 12288;

    float4v acc[4][4];
    #pragma unroll
    for (int i = 0; i < 4; ++i)
        #pragma unroll
        for (int j = 0; j < 4; ++j)
            acc[i][j] = (float4v){0.f, 0.f, 0.f, 0.f};

    for (int kt = 0; kt < KPAD; kt += 32) {
        #pragma unroll
        for (int c = 0; c < 8; ++c) {
            __builtin_amdgcn_global_load_lds(
                (const __attribute__((address_space(1))) void*)(srow + choff[c] + kt),
                (__attribute__((address_space(3))) void*)(ldsw + c * 512),
                16, 0, 0);
        }
        __syncthreads();

        half8 ah[4], bh[4], o4[4];
        #pragma unroll
        for (int i = 0; i < 4; ++i) ah[i] = *(const half8*)(sAh + aoff[i]);
        #pragma unroll
        for (int j = 0; j < 4; ++j) bh[j] = *(const half8*)(sBh + boff[j]);
        #pragma unroll
        for (int i = 0; i < 4; ++i)
            #pragma unroll
            for (int j = 0; j < 4; ++j)
                acc[i][j] = __builtin_amdgcn_mfma_f32_16x16x32_f16(ah[i], bh[j], acc[i][j], 0, 0, 0);
        #pragma unroll
        for (int j = 0; j < 4; ++j) o4[j] = *(const half8*)(sBl + boff[j]);
        #pragma unroll
        for (int i = 0; i < 4; ++i)
            #pragma unroll
            for (int j = 0; j < 4; ++j)
                acc[i][j] = __builtin_amdgcn_mfma_f32_16x16x32_f16(ah[i], o4[j], acc[i][j], 0, 0, 0);
        #pragma unroll
        for (int i = 0; i < 4; ++i) o4[i] = *(const half8*)(sAl + aoff[i]);
        #pragma unroll
        for (int i = 0; i < 4; ++i)
            #pragma unroll
            for (int j = 0; j < 4; ++j)
                acc[i][j] = __builtin_amdgcn_mfma_f32_16x16x32_f16(o4[i], bh[j], acc[i][j], 0, 0, 0);
        __syncthreads();
    }

    // ---- fused epilogue: score = 2*dot - strain[n]; per-row top-5 ----
    float st[4]; int okn[4];
    #pragma unroll
    for (int j = 0; j < 4; ++j) {
        int n = nb + nw + j * 16 + l15;
        okn[j] = (n < N_TRAIN);
        st[j] = okn[j] ? strain[n] : 0.f;
    }

    for (int h = 0; h < 2; ++h) {
        __syncthreads();
        if ((w & 1) == h) {
            #pragma unroll
            for (int i = 0; i < 4; ++i) {
                int r = i * 16 + q * 4;
                #pragma unroll
                for (int j = 0; j < 4; ++j) {
                    int col = nw + j * 16 + l15;
                    float4v v;
                    if (okn[j]) {
                        v = acc[i][j] * 2.0f;
                        v = v - st[j];
                    } else {
                        v = (float4v){-FLT_MAX, -FLT_MAX, -FLT_MAX, -FLT_MAX};
                    }
                    *(float4v*)(epi + col * 68 + r) = v;
                }
            }
        }
        __syncthreads();
        // scan: thread t -> row (t&63), col-quarter (t>>6)
        {
            int r = tid & 63, qq = tid >> 6;
            float tv[TOPK]; int ti[TOPK];
            #pragma unroll
            for (int s = 0; s < TOPK; ++s) { tv[s] = -FLT_MAX; ti[s] = 0x7fffffff; }
            for (int c = 0; c < 32; ++c) {
                int col = qq * 32 + c;
                float sc = epi[col * 68 + r];
                int n = nb + col;
                if (sc > tv[TOPK - 1] || (sc == tv[TOPK - 1] && n < ti[TOPK - 1])) {
                    INSERT5(tv, ti, sc, n);
                }
            }
            #pragma unroll
            for (int s = 0; s < TOPK; ++s) {
                lval[(r * 4 + qq) * TOPK + s] = tv[s];
                lidx[(r * 4 + qq) * TOPK + s] = ti[s];
            }
        }
        __syncthreads();
        if (tid < 64) {
            float tv[TOPK]; int ti[TOPK];
            #pragma unroll
            for (int s = 0; s < TOPK; ++s) { tv[s] = -FLT_MAX; ti[s] = 0x7fffffff; }
            for (int qq = 0; qq < 4; ++qq)
                #pragma unroll
                for (int s = 0; s < TOPK; ++s) {
                    float cv = lval[(tid * 4 + qq) * TOPK + s];
                    int ci = lidx[(tid * 4 + qq) * TOPK + s];
                    if (cv > tv[TOPK - 1] || (cv == tv[TOPK - 1] && ci < ti[TOPK - 1])) {
                        INSERT5(tv, ti, cv, ci);
                    }
                }
            int grow = mb + h * 64 + tid;
            #pragma unroll
            for (int s = 0; s < TOPK; ++s) {
                cval[((size_t)blockIdx.x * TOPK + s) * B_TEST + grow] = tv[s];
                cidx[((size_t)blockIdx.x * TOPK + s) * B_TEST + grow] = ti[s];
            }
        }
    }
}

// ---------------- fast path: merge per-block top-5, gather labels, vote ----------------
__global__ __launch_bounds__(256)
void knn_phaseB2(const float* __restrict__ cval, const int* __restrict__ cidx,
                 const int* __restrict__ y, int* __restrict__ out) {
    int b = blockIdx.x * blockDim.x + threadIdx.x;
    if (b >= B_TEST) return;
    float tv[TOPK]; int ti[TOPK];
    #pragma unroll
    for (int s = 0; s < TOPK; ++s) { tv[s] = -FLT_MAX; ti[s] = 0x7fffffff; }
    for (int c = 0; c < NBLK; ++c)
        #pragma unroll
        for (int s = 0; s < TOPK; ++s) {
            float cv = cval[((size_t)c * TOPK + s) * B_TEST + b];
            int ci = cidx[((size_t)c * TOPK + s) * B_TEST + b];
            if (cv > tv[TOPK - 1] || (cv == tv[TOPK - 1] && ci < ti[TOPK - 1])) {
                INSERT5(tv, ti, cv, ci);
            }
        }
    int lab[TOPK];
    #pragma unroll
    for (int s = 0; s < TOPK; ++s) lab[s] = y[ti[s]];
    int best_c = 0, best_cnt = -1;
    #pragma unroll
    for (int c = 0; c < N_CLASSES; ++c) {
        int cnt = 0;
        #pragma unroll
        for (int s = 0; s < TOPK; ++s) cnt += (lab[s] == c) ? 1 : 0;
        if (cnt > best_cnt) { best_cnt = cnt; best_c = c; }
    }
    out[b] = best_c;
}

// ================= fallback (round-1 fp32 path, known-correct) =================
#define FBM 64
#define FBN 64
#define FBK 16
#define FNCH 32
#define FCHUNK 1600

__global__ __launch_bounds__(256)
void knn_phaseA_fb(const float* __restrict__ xt, const float* __restrict__ xtr,
                   const float* __restrict__ strain,
                   float* __restrict__ cval, int* __restrict__ cidx) {
    __shared__ float As[FBK][FBM + 4];
    __shared__ float Bs[FBK][FBN + 4];
    __shared__ float lv[FBM][16][TOPK];
    __shared__ int   li[FBM][16][TOPK];

    const int tid = threadIdx.x;
    const int tx = tid & 15, ty = tid >> 4;
    const int b0 = blockIdx.x * FBM;
    const int chunk = blockIdx.y;
    const int n_base = chunk * FCHUNK;
    const int lrow = tid >> 2;
    const int lk4  = (tid & 3) * 4;

    float tv[4][TOPK]; int ti[4][TOPK];
    #pragma unroll
    for (int i = 0; i < 4; ++i)
        #pragma unroll
        for (int s = 0; s < TOPK; ++s) { tv[i][s] = -FLT_MAX; ti[i][s] = 0x7fffffff; }

    for (int nt = 0; nt < FCHUNK; nt += FBN) {
        const int n0 = n_base + nt;
        double accd[4][4];
        #pragma unroll
        for (int i = 0; i < 4; ++i)
            #pragma unroll
            for (int j = 0; j < 4; ++j) accd[i][j] = 0.0;

        for (int kt = 0; kt < D_DIM; kt += FBK) {
            float4 av = *(const float4*)(xt + (size_t)(b0 + lrow) * D_DIM + kt + lk4);
            As[lk4 + 0][lrow] = av.x; As[lk4 + 1][lrow] = av.y;
            As[lk4 + 2][lrow] = av.z; As[lk4 + 3][lrow] = av.w;
            int nr = n0 + lrow;
            float4 bv = make_float4(0.f, 0.f, 0.f, 0.f);
            if (nr < N_TRAIN) bv = *(const float4*)(xtr + (size_t)nr * D_DIM + kt + lk4);
            Bs[lk4 + 0][lrow] = bv.x; Bs[lk4 + 1][lrow] = bv.y;
            Bs[lk4 + 2][lrow] = bv.z; Bs[lk4 + 3][lrow] = bv.w;
            __syncthreads();

            float accf[4][4] = {{0.f}};
            #pragma unroll
            for (int k = 0; k < FBK; ++k) {
                float a[4], b[4];
                #pragma unroll
                for (int i = 0; i < 4; ++i) a[i] = As[k][ty * 4 + i];
                #pragma unroll
                for (int j = 0; j < 4; ++j) b[j] = Bs[k][tx * 4 + j];
                #pragma unroll
                for (int i = 0; i < 4; ++i)
                    #pragma unroll
                    for (int j = 0; j < 4; ++j) accf[i][j] += a[i] * b[j];
            }
            #pragma unroll
            for (int i = 0; i < 4; ++i)
                #pragma unroll
                for (int j = 0; j < 4; ++j) accd[i][j] += (double)accf[i][j];
            __syncthreads();
        }

        #pragma unroll
        for (int j = 0; j < 4; ++j) {
            int n = n0 + tx * 4 + j;
            if (n < N_TRAIN) {
                float sn = strain[n];
                #pragma unroll
                for (int i = 0; i < 4; ++i) {
                    float sc = (float)(2.0 * accd[i][j] - (double)sn);
                    if (sc > tv[i][TOPK - 1] ||
                        (sc == tv[i][TOPK - 1] && n < ti[i][TOPK - 1])) {
                        INSERT5(tv[i], ti[i], sc, n);
                    }
                }
            }
        }
    }

    #pragma unroll
    for (int i = 0; i < 4; ++i)
        #pragma unroll
        for (int s = 0; s < TOPK; ++s) {
            lv[ty * 4 + i][tx][s] = tv[i][s];
            li[ty * 4 + i][tx][s] = ti[i][s];
        }
    __syncthreads();

    if (tid < FBM) {
        float bv5[TOPK]; int bi5[TOPK];
        #pragma unroll
        for (int s = 0; s < TOPK; ++s) { bv5[s] = -FLT_MAX; bi5[s] = 0x7fffffff; }
        for (int t = 0; t < 16; ++t)
            #pragma unroll
            for (int s = 0; s < TOPK; ++s) {
                float cv = lv[tid][t][s]; int ci = li[tid][t][s];
                if (cv > bv5[TOPK - 1] || (cv == bv5[TOPK - 1] && ci < bi5[TOPK - 1])) {
                    INSERT5(bv5, bi5, cv, ci);
                }
            }
        size_t base = ((size_t)(b0 + tid) * FNCH + chunk) * TOPK;
        #pragma unroll
        for (int s = 0; s < TOPK; ++s) { cval[base + s] = bv5[s]; cidx[base + s] = bi5[s]; }
    }
}

__global__ __launch_bounds__(256)
void knn_phaseB_fb(const float* __restrict__ cval, const int* __restrict__ cidx,
                   const int* __restrict__ y, int* __restrict__ out) {
    int b = blockIdx.x * blockDim.x + threadIdx.x;
    if (b >= B_TEST) return;
    const float* v = cval + (size_t)b * FNCH * TOPK;
    const int* ix = cidx + (size_t)b * FNCH * TOPK;
    float bv5[TOPK]; int bi5[TOPK];
    #pragma unroll
    for (int s = 0; s < TOPK; ++s) { bv5[s] = -FLT_MAX; bi5[s] = 0x7fffffff; }
    for (int t = 0; t < FNCH * TOPK; ++t) {
        float cv = v[t]; int ci = ix[t];
        if (cv > bv5[TOPK - 1] || (cv == bv5[TOPK - 1] && ci < bi5[TOPK - 1])) {
            INSERT5(bv5, bi5, cv, ci);
        }
    }
    int lab[TOPK];
    #pragma unroll
    for (int s = 0; s < TOPK; ++s) lab[s] = y[bi5[s]];
    int best_c = 0, best_cnt = -1;
    #pragma unroll
    for (int c = 0; c < N_CLASSES; ++c) {
        int cnt = 0;
        #pragma unroll
        for (int s = 0; s < TOPK; ++s) cnt += (lab[s] == c) ? 1 : 0;
        if (cnt > best_cnt) { best_cnt = cnt; best_c = c; }
    }
    out[b] = best_c;
}

// =====================================================================
extern "C" void kernel_launch(void* const* d_in, const int* in_sizes, int n_in,
                              void* d_out, int out_size, void* d_ws, size_t ws_size,
                              hipStream_t stream) {
    const float* x_test  = (const float*)d_in[0];
    const float* x_train = (const float*)d_in[1];
    const int*   y_train = (const int*)d_in[2];
    int* out = (int*)d_out;

    // fast-path workspace layout (bytes)
    const size_t off_strain = 0;
    const size_t off_Bh = 200192;
    const size_t off_Bl = off_Bh + (size_t)NPAD * KPAD * 2;       // 80,076,800 each
    const size_t off_Ah = off_Bl + (size_t)NPAD * KPAD * 2;
    const size_t off_Al = off_Ah + (size_t)B_TEST * KPAD * 2;     // 3,276,800 each
    const size_t off_cv = off_Al + (size_t)B_TEST * KPAD * 2;
    const size_t off_ci = off_cv + (size_t)NBLK * TOPK * B_TEST * 4;  // 16,015,360 each
    const size_t need   = off_ci + (size_t)NBLK * TOPK * B_TEST * 4;  // ~198.9 MB

    char* ws = (char*)d_ws;
    float* strain = (float*)(ws + off_strain);

    rowsum_kernel<<<N_TRAIN / 4, 256, 0, stream>>>(x_train, strain);

    if (ws_size >= need) {
        _Float16* Bh = (_Float16*)(ws + off_Bh);
        _Float16* Bl = (_Float16*)(ws + off_Bl);
        _Float16* Ah = (_Float16*)(ws + off_Ah);
        _Float16* Al = (_Float16*)(ws + off_Al);
        float* cval = (float*)(ws + off_cv);
        int*   cidx = (int*)(ws + off_ci);

        long tg_train = (long)NPAD * 100;
        long tg_test  = (long)B_TEST * 100;
        split_f16<<<(int)((tg_train + 255) / 256), 256, 0, stream>>>(x_train, Bh, Bl, N_TRAIN, tg_train);
        split_f16<<<(int)((tg_test + 255) / 256), 256, 0, stream>>>(x_test, Ah, Al, B_TEST, tg_test);

        dim3 grid(NBLK, B_TEST / 128);
        knn_mfma<<<grid, 256, 0, stream>>>(Ah, Al, Bh, Bl, strain, cval, cidx);

        knn_phaseB2<<<(B_TEST + 255) / 256, 256, 0, stream>>>(cval, cidx, y_train, out);
    } else {
        float* cval = (float*)(ws + 200192);
        int*   cidx = (int*)(ws + 200192 + (size_t)B_TEST * FNCH * TOPK * 4);

        dim3 gridA(B_TEST / FBM, FNCH);
        knn_phaseA_fb<<<gridA, 256, 0, stream>>>(x_test, x_train, strain, cval, cidx);
        knn_phaseB_fb<<<(B_TEST + 255) / 256, 256, 0, stream>>>(cval, cidx, y_train, out);
    }
}

// Round 3
// 1021.807 us; speedup vs baseline: 3.8241x; 1.6289x over previous
//
#include <hip/hip_runtime.h>
#include <float.h>
#include <stdint.h>

#define D_DIM 784
#define KPAD 800
#define N_TRAIN 50000
#define NPAD 50048
#define B_TEST 2048
#define N_CLASSES 10
#define TOPK 5
#define NBLK 391        // ceil(50048/128) n-blocks in fast path

typedef __attribute__((ext_vector_type(8))) _Float16 half8;
typedef __attribute__((ext_vector_type(4))) float float4v;

// branch-free sorted-insert of (cv,ci) into 5-deep list (val desc, idx asc)
#define INSERT5(tvarr, tiarr, CV, CI)                                   \
    {                                                                   \
        float _cv = (CV); int _ci = (CI);                               \
        _Pragma("unroll")                                               \
        for (int _s = 0; _s < TOPK; ++_s) {                             \
            bool _bet = (_cv > tvarr[_s]) ||                            \
                        (_cv == tvarr[_s] && _ci < tiarr[_s]);          \
            float _fv = _bet ? tvarr[_s] : _cv;                         \
            int   _fi = _bet ? tiarr[_s] : _ci;                         \
            tvarr[_s] = _bet ? _cv : tvarr[_s];                         \
            tiarr[_s] = _bet ? _ci : tiarr[_s];                         \
            _cv = _fv; _ci = _fi;                                       \
        }                                                               \
    }

// ---------------- rowsum of x_train (shared by both paths) ----------------
__global__ __launch_bounds__(256)
void rowsum_kernel(const float* __restrict__ x, float* __restrict__ s) {
    int row = blockIdx.x * 4 + (threadIdx.x >> 6);
    int lane = threadIdx.x & 63;
    if (row >= N_TRAIN) return;
    const float* p = x + (size_t)row * D_DIM;
    float acc = 0.f;
    for (int i = lane; i < D_DIM; i += 64) acc += p[i];
    #pragma unroll
    for (int off = 32; off > 0; off >>= 1) acc += __shfl_down(acc, off, 64);
    if (lane == 0) s[row] = acc;
}

// ---------------- fast path: split fp32 -> f16 hi/lo, padded ----------------
__global__ __launch_bounds__(256)
void split_f16(const float* __restrict__ src, _Float16* __restrict__ hi,
               _Float16* __restrict__ lo, int rows_src, long total_groups) {
    long idx = (long)blockIdx.x * 256 + threadIdx.x;   // one 8-elem group
    if (idx >= total_groups) return;
    int r = (int)(idx / 100);
    int g = (int)(idx % 100);
    float v[8];
    if (r < rows_src && g < 98) {
        const float* p = src + (size_t)r * D_DIM + g * 8;
        float4 a = *(const float4*)p;
        float4 b = *(const float4*)(p + 4);
        v[0]=a.x; v[1]=a.y; v[2]=a.z; v[3]=a.w;
        v[4]=b.x; v[5]=b.y; v[6]=b.z; v[7]=b.w;
    } else {
        #pragma unroll
        for (int i = 0; i < 8; ++i) v[i] = 0.f;
    }
    half8 h8, l8;
    #pragma unroll
    for (int i = 0; i < 8; ++i) {
        _Float16 h = (_Float16)v[i];
        h8[i] = h;
        l8[i] = (_Float16)(v[i] - (float)h);
    }
    size_t o = (size_t)r * KPAD + g * 8;
    *(half8*)(hi + o) = h8;
    *(half8*)(lo + o) = l8;
}

// ---------------- fast path: MFMA split-f16 GEMM + fused top-5 ----------------
// grid: 6272 blocks, XCD-private 4m x 4n supertiles for L2 locality:
//   16 consecutive same-XCD blocks share 4 A-panels + 4 B-panels (3.2 MB < 4 MB L2)
__global__ __launch_bounds__(256, 3)
void knn_mfma(const _Float16* __restrict__ Ah, const _Float16* __restrict__ Al,
              const _Float16* __restrict__ Bh, const _Float16* __restrict__ Bl,
              const float* __restrict__ strain,
              float* __restrict__ cval, int* __restrict__ cidx) {
    const int bid = blockIdx.x;
    const int xcd = bid & 7;
    const int sidx = bid >> 3;                       // 0..783
    const int st_g = (sidx >> 4) * 8 + xcd;          // supertile 0..391
    const int r16 = sidx & 15;
    const int mblk = (st_g & 3) * 4 + (r16 & 3);
    const int nchunk = (st_g >> 2) * 4 + (r16 >> 2);
    if (nchunk >= NBLK) return;                      // padded supertile slot

    __shared__ char lds_raw[45056] __attribute__((aligned(16)));
    _Float16* stage = (_Float16*)lds_raw;            // 4 tiles x 8192 B
    float* epi  = (float*)lds_raw;                   // [128 cols][68] floats
    float* lval = (float*)(lds_raw + 34816);         // [64][4][5]
    int*   lidx = (int*)(lds_raw + 34816 + 5120);    // [64][4][5]

    const int tid = threadIdx.x;
    const int w = tid >> 6, lane = tid & 63;
    const int l15 = lane & 15, q = lane >> 4;
    const int mb = mblk * 128;
    const int nb = nchunk * 128;
    const int mw = (w & 1) * 64, nw = (w >> 1) * 64;

    // wave w stages one array: 0=Ah 1=Al 2=Bh 3=Bl
    const _Float16* srcs[4] = {Ah, Al, Bh, Bl};
    const _Float16* src = srcs[w];
    const int rowbase = (w < 2) ? mb : nb;
    const _Float16* srow = src + (size_t)rowbase * KPAD;
    _Float16* ldsw = stage + w * 4096;               // halves

    // per-chunk swizzled global offsets (halves): slot = c*64+lane
    int choff[8];
    #pragma unroll
    for (int c = 0; c < 8; ++c) {
        int slot = c * 64 + lane;
        int m = slot >> 2;
        int k8 = (slot & 3) ^ ((m >> 1) & 3);
        choff[c] = m * KPAD + k8 * 8;
    }
    // frag LDS offsets (halves): slot*8
    int aoff[4], boff[4];
    #pragma unroll
    for (int i = 0; i < 4; ++i) {
        int ma = mw + i * 16 + l15;
        aoff[i] = (4 * ma + (q ^ ((ma >> 1) & 3))) * 8;
        int nr = nw + i * 16 + l15;
        boff[i] = (4 * nr + (q ^ ((nr >> 1) & 3))) * 8;
    }

    const _Float16* sAh = stage;
    const _Float16* sAl = stage + 4096;
    const _Float16* sBh = stage + 8192;
    const _Float16* sBl = stage + 12288;

    float4v acc[4][4];
    #pragma unroll
    for (int i = 0; i < 4; ++i)
        #pragma unroll
        for (int j = 0; j < 4; ++j)
            acc[i][j] = (float4v){0.f, 0.f, 0.f, 0.f};

    for (int kt = 0; kt < KPAD; kt += 32) {
        #pragma unroll
        for (int c = 0; c < 8; ++c) {
            __builtin_amdgcn_global_load_lds(
                (const __attribute__((address_space(1))) void*)(srow + choff[c] + kt),
                (__attribute__((address_space(3))) void*)(ldsw + c * 512),
                16, 0, 0);
        }
        __syncthreads();

        half8 ah[4], bh[4], o4[4];
        #pragma unroll
        for (int i = 0; i < 4; ++i) ah[i] = *(const half8*)(sAh + aoff[i]);
        #pragma unroll
        for (int j = 0; j < 4; ++j) bh[j] = *(const half8*)(sBh + boff[j]);
        #pragma unroll
        for (int i = 0; i < 4; ++i)
            #pragma unroll
            for (int j = 0; j < 4; ++j)
                acc[i][j] = __builtin_amdgcn_mfma_f32_16x16x32_f16(ah[i], bh[j], acc[i][j], 0, 0, 0);
        #pragma unroll
        for (int j = 0; j < 4; ++j) o4[j] = *(const half8*)(sBl + boff[j]);
        #pragma unroll
        for (int i = 0; i < 4; ++i)
            #pragma unroll
            for (int j = 0; j < 4; ++j)
                acc[i][j] = __builtin_amdgcn_mfma_f32_16x16x32_f16(ah[i], o4[j], acc[i][j], 0, 0, 0);
        #pragma unroll
        for (int i = 0; i < 4; ++i) o4[i] = *(const half8*)(sAl + aoff[i]);
        #pragma unroll
        for (int i = 0; i < 4; ++i)
            #pragma unroll
            for (int j = 0; j < 4; ++j)
                acc[i][j] = __builtin_amdgcn_mfma_f32_16x16x32_f16(o4[i], bh[j], acc[i][j], 0, 0, 0);
        __syncthreads();
    }

    // ---- fused epilogue: score = 2*dot - strain[n]; per-row top-5 ----
    float st[4]; int okn[4];
    #pragma unroll
    for (int j = 0; j < 4; ++j) {
        int n = nb + nw + j * 16 + l15;
        okn[j] = (n < N_TRAIN);
        st[j] = okn[j] ? strain[n] : 0.f;
    }

    for (int h = 0; h < 2; ++h) {
        __syncthreads();
        if ((w & 1) == h) {
            #pragma unroll
            for (int i = 0; i < 4; ++i) {
                int r = i * 16 + q * 4;
                #pragma unroll
                for (int j = 0; j < 4; ++j) {
                    int col = nw + j * 16 + l15;
                    float4v v;
                    if (okn[j]) {
                        v = acc[i][j] * 2.0f;
                        v = v - st[j];
                    } else {
                        v = (float4v){-FLT_MAX, -FLT_MAX, -FLT_MAX, -FLT_MAX};
                    }
                    *(float4v*)(epi + col * 68 + r) = v;
                }
            }
        }
        __syncthreads();
        // scan: thread t -> row (t&63), col-quarter (t>>6)
        {
            int r = tid & 63, qq = tid >> 6;
            float tv[TOPK]; int ti[TOPK];
            #pragma unroll
            for (int s = 0; s < TOPK; ++s) { tv[s] = -FLT_MAX; ti[s] = 0x7fffffff; }
            for (int c = 0; c < 32; ++c) {
                int col = qq * 32 + c;
                float sc = epi[col * 68 + r];
                int n = nb + col;
                if (sc > tv[TOPK - 1] || (sc == tv[TOPK - 1] && n < ti[TOPK - 1])) {
                    INSERT5(tv, ti, sc, n);
                }
            }
            #pragma unroll
            for (int s = 0; s < TOPK; ++s) {
                lval[(r * 4 + qq) * TOPK + s] = tv[s];
                lidx[(r * 4 + qq) * TOPK + s] = ti[s];
            }
        }
        __syncthreads();
        if (tid < 64) {
            float tv[TOPK]; int ti[TOPK];
            #pragma unroll
            for (int s = 0; s < TOPK; ++s) { tv[s] = -FLT_MAX; ti[s] = 0x7fffffff; }
            for (int qq = 0; qq < 4; ++qq)
                #pragma unroll
                for (int s = 0; s < TOPK; ++s) {
                    float cv = lval[(tid * 4 + qq) * TOPK + s];
                    int ci = lidx[(tid * 4 + qq) * TOPK + s];
                    if (cv > tv[TOPK - 1] || (cv == tv[TOPK - 1] && ci < ti[TOPK - 1])) {
                        INSERT5(tv, ti, cv, ci);
                    }
                }
            int grow = mb + h * 64 + tid;
            #pragma unroll
            for (int s = 0; s < TOPK; ++s) {
                cval[((size_t)nchunk * TOPK + s) * B_TEST + grow] = tv[s];
                cidx[((size_t)nchunk * TOPK + s) * B_TEST + grow] = ti[s];
            }
        }
    }
}

// ---------------- fast path: parallel merge + vote (one block per test row) ----------------
__global__ __launch_bounds__(256)
void knn_phaseB2(const float* __restrict__ cval, const int* __restrict__ cidx,
                 const int* __restrict__ y, int* __restrict__ out) {
    __shared__ float sv[256][TOPK];
    __shared__ int   si[256][TOPK];
    const int b = blockIdx.x;
    const int t = threadIdx.x;

    float tv[TOPK]; int ti[TOPK];
    #pragma unroll
    for (int s = 0; s < TOPK; ++s) { tv[s] = -FLT_MAX; ti[s] = 0x7fffffff; }

    // parallel scan of the 391*5 candidates for this row
    for (int e = t; e < NBLK * TOPK; e += 256) {
        float cv = cval[(size_t)e * B_TEST + b];
        int ci = cidx[(size_t)e * B_TEST + b];
        INSERT5(tv, ti, cv, ci);
    }
    #pragma unroll
    for (int s = 0; s < TOPK; ++s) { sv[t][s] = tv[s]; si[t][s] = ti[s]; }
    __syncthreads();

    // tree merge 256 -> 1
    for (int off = 128; off >= 1; off >>= 1) {
        if (t < off) {
            #pragma unroll
            for (int s = 0; s < TOPK; ++s) {
                float cv = sv[t + off][s]; int ci = si[t + off][s];
                INSERT5(tv, ti, cv, ci);
            }
            #pragma unroll
            for (int s = 0; s < TOPK; ++s) { sv[t][s] = tv[s]; si[t][s] = ti[s]; }
        }
        __syncthreads();
    }

    if (t == 0) {
        int lab[TOPK];
        #pragma unroll
        for (int s = 0; s < TOPK; ++s) lab[s] = y[ti[s]];
        int best_c = 0, best_cnt = -1;
        #pragma unroll
        for (int c = 0; c < N_CLASSES; ++c) {
            int cnt = 0;
            #pragma unroll
            for (int s = 0; s < TOPK; ++s) cnt += (lab[s] == c) ? 1 : 0;
            if (cnt > best_cnt) { best_cnt = cnt; best_c = c; }
        }
        out[b] = best_c;
    }
}

// ================= fallback (round-1 fp32 path, known-correct) =================
#define FBM 64
#define FBN 64
#define FBK 16
#define FNCH 32
#define FCHUNK 1600

__global__ __launch_bounds__(256)
void knn_phaseA_fb(const float* __restrict__ xt, const float* __restrict__ xtr,
                   const float* __restrict__ strain,
                   float* __restrict__ cval, int* __restrict__ cidx) {
    __shared__ float As[FBK][FBM + 4];
    __shared__ float Bs[FBK][FBN + 4];
    __shared__ float lv[FBM][16][TOPK];
    __shared__ int   li[FBM][16][TOPK];

    const int tid = threadIdx.x;
    const int tx = tid & 15, ty = tid >> 4;
    const int b0 = blockIdx.x * FBM;
    const int chunk = blockIdx.y;
    const int n_base = chunk * FCHUNK;
    const int lrow = tid >> 2;
    const int lk4  = (tid & 3) * 4;

    float tv[4][TOPK]; int ti[4][TOPK];
    #pragma unroll
    for (int i = 0; i < 4; ++i)
        #pragma unroll
        for (int s = 0; s < TOPK; ++s) { tv[i][s] = -FLT_MAX; ti[i][s] = 0x7fffffff; }

    for (int nt = 0; nt < FCHUNK; nt += FBN) {
        const int n0 = n_base + nt;
        double accd[4][4];
        #pragma unroll
        for (int i = 0; i < 4; ++i)
            #pragma unroll
            for (int j = 0; j < 4; ++j) accd[i][j] = 0.0;

        for (int kt = 0; kt < D_DIM; kt += FBK) {
            float4 av = *(const float4*)(xt + (size_t)(b0 + lrow) * D_DIM + kt + lk4);
            As[lk4 + 0][lrow] = av.x; As[lk4 + 1][lrow] = av.y;
            As[lk4 + 2][lrow] = av.z; As[lk4 + 3][lrow] = av.w;
            int nr = n0 + lrow;
            float4 bv = make_float4(0.f, 0.f, 0.f, 0.f);
            if (nr < N_TRAIN) bv = *(const float4*)(xtr + (size_t)nr * D_DIM + kt + lk4);
            Bs[lk4 + 0][lrow] = bv.x; Bs[lk4 + 1][lrow] = bv.y;
            Bs[lk4 + 2][lrow] = bv.z; Bs[lk4 + 3][lrow] = bv.w;
            __syncthreads();

            float accf[4][4] = {{0.f}};
            #pragma unroll
            for (int k = 0; k < FBK; ++k) {
                float a[4], b[4];
                #pragma unroll
                for (int i = 0; i < 4; ++i) a[i] = As[k][ty * 4 + i];
                #pragma unroll
                for (int j = 0; j < 4; ++j) b[j] = Bs[k][tx * 4 + j];
                #pragma unroll
                for (int i = 0; i < 4; ++i)
                    #pragma unroll
                    for (int j = 0; j < 4; ++j) accf[i][j] += a[i] * b[j];
            }
            #pragma unroll
            for (int i = 0; i < 4; ++i)
                #pragma unroll
                for (int j = 0; j < 4; ++j) accd[i][j] += (double)accf[i][j];
            __syncthreads();
        }

        #pragma unroll
        for (int j = 0; j < 4; ++j) {
            int n = n0 + tx * 4 + j;
            if (n < N_TRAIN) {
                float sn = strain[n];
                #pragma unroll
                for (int i = 0; i < 4; ++i) {
                    float sc = (float)(2.0 * accd[i][j] - (double)sn);
                    if (sc > tv[i][TOPK - 1] ||
                        (sc == tv[i][TOPK - 1] && n < ti[i][TOPK - 1])) {
                        INSERT5(tv[i], ti[i], sc, n);
                    }
                }
            }
        }
    }

    #pragma unroll
    for (int i = 0; i < 4; ++i)
        #pragma unroll
        for (int s = 0; s < TOPK; ++s) {
            lv[ty * 4 + i][tx][s] = tv[i][s];
            li[ty * 4 + i][tx][s] = ti[i][s];
        }
    __syncthreads();

    if (tid < FBM) {
        float bv5[TOPK]; int bi5[TOPK];
        #pragma unroll
        for (int s = 0; s < TOPK; ++s) { bv5[s] = -FLT_MAX; bi5[s] = 0x7fffffff; }
        for (int t = 0; t < 16; ++t)
            #pragma unroll
            for (int s = 0; s < TOPK; ++s) {
                float cv = lv[tid][t][s]; int ci = li[tid][t][s];
                if (cv > bv5[TOPK - 1] || (cv == bv5[TOPK - 1] && ci < bi5[TOPK - 1])) {
                    INSERT5(bv5, bi5, cv, ci);
                }
            }
        size_t base = ((size_t)(b0 + tid) * FNCH + chunk) * TOPK;
        #pragma unroll
        for (int s = 0; s < TOPK; ++s) { cval[base + s] = bv5[s]; cidx[base + s] = bi5[s]; }
    }
}

__global__ __launch_bounds__(256)
void knn_phaseB_fb(const float* __restrict__ cval, const int* __restrict__ cidx,
                   const int* __restrict__ y, int* __restrict__ out) {
    int b = blockIdx.x * blockDim.x + threadIdx.x;
    if (b >= B_TEST) return;
    const float* v = cval + (size_t)b * FNCH * TOPK;
    const int* ix = cidx + (size_t)b * FNCH * TOPK;
    float bv5[TOPK]; int bi5[TOPK];
    #pragma unroll
    for (int s = 0; s < TOPK; ++s) { bv5[s] = -FLT_MAX; bi5[s] = 0x7fffffff; }
    for (int t = 0; t < FNCH * TOPK; ++t) {
        float cv = v[t]; int ci = ix[t];
        if (cv > bv5[TOPK - 1] || (cv == bv5[TOPK - 1] && ci < bi5[TOPK - 1])) {
            INSERT5(bv5, bi5, cv, ci);
        }
    }
    int lab[TOPK];
    #pragma unroll
    for (int s = 0; s < TOPK; ++s) lab[s] = y[bi5[s]];
    int best_c = 0, best_cnt = -1;
    #pragma unroll
    for (int c = 0; c < N_CLASSES; ++c) {
        int cnt = 0;
        #pragma unroll
        for (int s = 0; s < TOPK; ++s) cnt += (lab[s] == c) ? 1 : 0;
        if (cnt > best_cnt) { best_cnt = cnt; best_c = c; }
    }
    out[b] = best_c;
}

// =====================================================================
extern "C" void kernel_launch(void* const* d_in, const int* in_sizes, int n_in,
                              void* d_out, int out_size, void* d_ws, size_t ws_size,
                              hipStream_t stream) {
    const float* x_test  = (const float*)d_in[0];
    const float* x_train = (const float*)d_in[1];
    const int*   y_train = (const int*)d_in[2];
    int* out = (int*)d_out;

    // fast-path workspace layout (bytes)
    const size_t off_strain = 0;
    const size_t off_Bh = 200192;
    const size_t off_Bl = off_Bh + (size_t)NPAD * KPAD * 2;       // 80,076,800 each
    const size_t off_Ah = off_Bl + (size_t)NPAD * KPAD * 2;
    const size_t off_Al = off_Ah + (size_t)B_TEST * KPAD * 2;     // 3,276,800 each
    const size_t off_cv = off_Al + (size_t)B_TEST * KPAD * 2;
    const size_t off_ci = off_cv + (size_t)NBLK * TOPK * B_TEST * 4;  // 16,015,360 each
    const size_t need   = off_ci + (size_t)NBLK * TOPK * B_TEST * 4;  // ~198.9 MB

    char* ws = (char*)d_ws;
    float* strain = (float*)(ws + off_strain);

    rowsum_kernel<<<N_TRAIN / 4, 256, 0, stream>>>(x_train, strain);

    if (ws_size >= need) {
        _Float16* Bh = (_Float16*)(ws + off_Bh);
        _Float16* Bl = (_Float16*)(ws + off_Bl);
        _Float16* Ah = (_Float16*)(ws + off_Ah);
        _Float16* Al = (_Float16*)(ws + off_Al);
        float* cval = (float*)(ws + off_cv);
        int*   cidx = (int*)(ws + off_ci);

        long tg_train = (long)NPAD * 100;
        long tg_test  = (long)B_TEST * 100;
        split_f16<<<(int)((tg_train + 255) / 256), 256, 0, stream>>>(x_train, Bh, Bl, N_TRAIN, tg_train);
        split_f16<<<(int)((tg_test + 255) / 256), 256, 0, stream>>>(x_test, Ah, Al, B_TEST, tg_test);

        knn_mfma<<<6272, 256, 0, stream>>>(Ah, Al, Bh, Bl, strain, cval, cidx);

        knn_phaseB2<<<B_TEST, 256, 0, stream>>>(cval, cidx, y_train, out);
    } else {
        float* cval = (float*)(ws + 200192);
        int*   cidx = (int*)(ws + 200192 + (size_t)B_TEST * FNCH * TOPK * 4);

        dim3 gridA(B_TEST / FBM, FNCH);
        knn_phaseA_fb<<<gridA, 256, 0, stream>>>(x_test, x_train, strain, cval, cidx);
        knn_phaseB_fb<<<(B_TEST + 255) / 256, 256, 0, stream>>>(cval, cidx, y_train, out);
    }
}

// Round 4
// 893.012 us; speedup vs baseline: 4.3756x; 1.1442x over previous
//
#include <hip/hip_runtime.h>
#include <float.h>
#include <stdint.h>

#define D_DIM 784
#define KPAD 832            // 13 x 64
#define NGRP 104            // KPAD/8 groups per row in split
#define N_TRAIN 50000
#define NPAD 50048
#define B_TEST 2048
#define N_CLASSES 10
#define TOPK 5
#define NBLK 391            // ceil(50048/128)
#define GTOP 16             // global candidate set size for exact rescore

typedef __attribute__((ext_vector_type(8))) _Float16 half8;
typedef __attribute__((ext_vector_type(4))) float float4v;

// branch-free sorted-insert into K-deep list (val desc, idx asc)
template <int K>
__device__ inline void insertK(float* tv, int* ti, float cv, int ci) {
    #pragma unroll
    for (int s = 0; s < K; ++s) {
        bool bet = (cv > tv[s]) || (cv == tv[s] && ci < ti[s]);
        float fv = bet ? tv[s] : cv;
        int   fi = bet ? ti[s] : ci;
        tv[s] = bet ? cv : tv[s];
        ti[s] = bet ? ci : ti[s];
        cv = fv; ci = fi;
    }
}

#define INSERT5(tvarr, tiarr, CV, CI) insertK<TOPK>(tvarr, tiarr, (CV), (CI))

// ---------------- rowsum of x_train (approx pass uses fp32) ----------------
__global__ __launch_bounds__(256)
void rowsum_kernel(const float* __restrict__ x, float* __restrict__ s) {
    int row = blockIdx.x * 4 + (threadIdx.x >> 6);
    int lane = threadIdx.x & 63;
    if (row >= N_TRAIN) return;
    const float* p = x + (size_t)row * D_DIM;
    float acc = 0.f;
    for (int i = lane; i < D_DIM; i += 64) acc += p[i];
    #pragma unroll
    for (int off = 32; off > 0; off >>= 1) acc += __shfl_down(acc, off, 64);
    if (lane == 0) s[row] = acc;
}

// ---------------- split fp32 -> f16 hi only, K padded to 832 ----------------
__global__ __launch_bounds__(256)
void split_h(const float* __restrict__ src, _Float16* __restrict__ hi,
             int rows_src, int total_groups) {
    int idx = blockIdx.x * 256 + threadIdx.x;   // one 8-elem group
    if (idx >= total_groups) return;
    int r = idx / NGRP;
    int g = idx % NGRP;
    float v[8];
    if (r < rows_src && g < 98) {               // 98*8 = 784 real dims
        const float* p = src + (size_t)r * D_DIM + g * 8;
        float4 a = *(const float4*)p;
        float4 b = *(const float4*)(p + 4);
        v[0]=a.x; v[1]=a.y; v[2]=a.z; v[3]=a.w;
        v[4]=b.x; v[5]=b.y; v[6]=b.z; v[7]=b.w;
    } else {
        #pragma unroll
        for (int i = 0; i < 8; ++i) v[i] = 0.f;
    }
    half8 h8;
    #pragma unroll
    for (int i = 0; i < 8; ++i) h8[i] = (_Float16)v[i];
    *(half8*)(hi + (size_t)r * KPAD + g * 8) = h8;
}

// ---------------- 1-term f16 MFMA GEMM + fused per-chunk top-5 ----------------
// grid 6272: XCD-private 4m x 4n supertiles (working set 1.7 MB < 4 MB XCD-L2)
__global__ __launch_bounds__(256, 3)
void knn_mfma(const _Float16* __restrict__ Ah, const _Float16* __restrict__ Bh,
              const float* __restrict__ strain,
              float* __restrict__ cval, int* __restrict__ cidx) {
    const int bid = blockIdx.x;
    const int xcd = bid & 7;
    const int sidx = bid >> 3;
    const int st_g = (sidx >> 4) * 8 + xcd;
    const int r16 = sidx & 15;
    const int mblk = (st_g & 3) * 4 + (r16 & 3);
    const int nchunk = (st_g >> 2) * 4 + (r16 >> 2);
    if (nchunk >= NBLK) return;

    __shared__ char lds_raw[51200] __attribute__((aligned(16)));
    _Float16* stage = (_Float16*)lds_raw;            // 2 tiles x 16 KB
    float* epi  = (float*)lds_raw;                   // [128 cols][68] floats
    float* lval = (float*)(lds_raw + 34816);         // [64][4][5]
    int*   lidx = (int*)(lds_raw + 34816 + 8192);    // [64][4][5]

    const int tid = threadIdx.x;
    const int w = tid >> 6, lane = tid & 63;
    const int l15 = lane & 15, q = lane >> 4;
    const int mb = mblk * 128, nb = nchunk * 128;
    const int mw = (w & 1) * 64, nw = (w >> 1) * 64;

    // staging: wave w loads half-tile: tile = w>>1 (0=A,1=B), half = w&1
    const int s_tile = w >> 1, s_half = w & 1;
    const _Float16* sbase = (s_tile == 0) ? (Ah + (size_t)mb * KPAD)
                                          : (Bh + (size_t)nb * KPAD);
    const _Float16* srow = sbase + (size_t)s_half * 64 * KPAD;
    _Float16* ldsw = stage + s_tile * 8192 + s_half * 4096;   // halves

    // staging source offsets (halves): LDS slot s=c*64+lane holds
    // row rl=s>>3, lds-k8=s&7, which maps to memory k8 = (s&7)^(rl&7)
    int choff[8];
    #pragma unroll
    for (int c = 0; c < 8; ++c) {
        int s = c * 64 + lane;
        int rl = s >> 3;
        int k8 = (s & 7) ^ (rl & 7);
        choff[c] = rl * KPAD + k8 * 8;
    }
    // fragment LDS offsets (halves), slot' = (k32*4+q) ^ (r&7) -> 2-way bank (free)
    int aoff[4][2], boff[4][2];
    #pragma unroll
    for (int i = 0; i < 4; ++i)
        #pragma unroll
        for (int k32 = 0; k32 < 2; ++k32) {
            int r = mw + i * 16 + l15;
            aoff[i][k32] = (r * 8 + ((k32 * 4 + q) ^ (r & 7))) * 8;
            r = nw + i * 16 + l15;
            boff[i][k32] = (r * 8 + ((k32 * 4 + q) ^ (r & 7))) * 8;
        }

    float4v acc[4][4];
    #pragma unroll
    for (int i = 0; i < 4; ++i)
        #pragma unroll
        for (int j = 0; j < 4; ++j)
            acc[i][j] = (float4v){0.f, 0.f, 0.f, 0.f};

    for (int kt = 0; kt < KPAD; kt += 64) {
        #pragma unroll
        for (int c = 0; c < 8; ++c) {
            __builtin_amdgcn_global_load_lds(
                (const __attribute__((address_space(1))) void*)(srow + choff[c] + kt),
                (__attribute__((address_space(3))) void*)(ldsw + c * 512),
                16, 0, 0);
        }
        __syncthreads();
        #pragma unroll
        for (int k32 = 0; k32 < 2; ++k32) {
            half8 a[4], b[4];
            #pragma unroll
            for (int i = 0; i < 4; ++i) a[i] = *(const half8*)(stage + aoff[i][k32]);
            #pragma unroll
            for (int j = 0; j < 4; ++j) b[j] = *(const half8*)(stage + 8192 + boff[j][k32]);
            #pragma unroll
            for (int i = 0; i < 4; ++i)
                #pragma unroll
                for (int j = 0; j < 4; ++j)
                    acc[i][j] = __builtin_amdgcn_mfma_f32_16x16x32_f16(a[i], b[j], acc[i][j], 0, 0, 0);
        }
        __syncthreads();
    }

    // ---- fused epilogue: approx score = 2*dot - strain[n]; per-chunk top-5 ----
    float st[4]; int okn[4];
    #pragma unroll
    for (int j = 0; j < 4; ++j) {
        int n = nb + nw + j * 16 + l15;
        okn[j] = (n < N_TRAIN);
        st[j] = okn[j] ? strain[n] : 0.f;
    }

    for (int h = 0; h < 2; ++h) {
        __syncthreads();
        if ((w & 1) == h) {
            #pragma unroll
            for (int i = 0; i < 4; ++i) {
                int r = i * 16 + q * 4;
                #pragma unroll
                for (int j = 0; j < 4; ++j) {
                    int col = nw + j * 16 + l15;
                    float4v v;
                    if (okn[j]) {
                        v = acc[i][j] * 2.0f;
                        v = v - st[j];
                    } else {
                        v = (float4v){-FLT_MAX, -FLT_MAX, -FLT_MAX, -FLT_MAX};
                    }
                    *(float4v*)(epi + col * 68 + r) = v;
                }
            }
        }
        __syncthreads();
        {
            int r = tid & 63, qq = tid >> 6;
            float tv[TOPK]; int ti[TOPK];
            #pragma unroll
            for (int s = 0; s < TOPK; ++s) { tv[s] = -FLT_MAX; ti[s] = 0x7fffffff; }
            for (int c = 0; c < 32; ++c) {
                int col = qq * 32 + c;
                float sc = epi[col * 68 + r];
                int n = nb + col;
                if (sc > tv[TOPK - 1] || (sc == tv[TOPK - 1] && n < ti[TOPK - 1])) {
                    INSERT5(tv, ti, sc, n);
                }
            }
            #pragma unroll
            for (int s = 0; s < TOPK; ++s) {
                lval[(r * 4 + qq) * TOPK + s] = tv[s];
                lidx[(r * 4 + qq) * TOPK + s] = ti[s];
            }
        }
        __syncthreads();
        if (tid < 64) {
            float tv[TOPK]; int ti[TOPK];
            #pragma unroll
            for (int s = 0; s < TOPK; ++s) { tv[s] = -FLT_MAX; ti[s] = 0x7fffffff; }
            for (int qq = 0; qq < 4; ++qq)
                #pragma unroll
                for (int s = 0; s < TOPK; ++s) {
                    float cv = lval[(tid * 4 + qq) * TOPK + s];
                    int ci = lidx[(tid * 4 + qq) * TOPK + s];
                    if (cv > tv[TOPK - 1] || (cv == tv[TOPK - 1] && ci < ti[TOPK - 1])) {
                        INSERT5(tv, ti, cv, ci);
                    }
                }
            int grow = mb + h * 64 + tid;
            size_t base = ((size_t)grow * NBLK + nchunk) * TOPK;
            #pragma unroll
            for (int s = 0; s < TOPK; ++s) { cval[base + s] = tv[s]; cidx[base + s] = ti[s]; }
        }
    }
}

// ------- fused merge (approx top-16) + exact fp64 rescore + vote, 1 block/row -------
__global__ __launch_bounds__(256)
void knn_final(const float* __restrict__ cval, const int* __restrict__ cidx,
               const float* __restrict__ xt, const float* __restrict__ xtr,
               const int* __restrict__ y, int* __restrict__ out) {
    __shared__ float sv[256][GTOP];
    __shared__ int   si[256][GTOP];
    __shared__ double cs[GTOP];
    __shared__ int    cn[GTOP];
    const int b = blockIdx.x;
    const int t = threadIdx.x;

    float tv[GTOP]; int ti[GTOP];
    #pragma unroll
    for (int s = 0; s < GTOP; ++s) { tv[s] = -FLT_MAX; ti[s] = 0x7fffffff; }

    const float* vrow = cval + (size_t)b * NBLK * TOPK;
    const int*   irow = cidx + (size_t)b * NBLK * TOPK;
    for (int e = t; e < NBLK * TOPK; e += 256) {
        float cv = vrow[e]; int ci = irow[e];
        if (cv > tv[GTOP - 1] || (cv == tv[GTOP - 1] && ci < ti[GTOP - 1]))
            insertK<GTOP>(tv, ti, cv, ci);
    }
    #pragma unroll
    for (int s = 0; s < GTOP; ++s) { sv[t][s] = tv[s]; si[t][s] = ti[s]; }
    __syncthreads();

    for (int off = 128; off >= 1; off >>= 1) {
        if (t < off) {
            #pragma unroll
            for (int s = 0; s < GTOP; ++s) {
                float cv = sv[t + off][s]; int ci = si[t + off][s];
                if (cv > tv[GTOP - 1] || (cv == tv[GTOP - 1] && ci < ti[GTOP - 1]))
                    insertK<GTOP>(tv, ti, cv, ci);
            }
            #pragma unroll
            for (int s = 0; s < GTOP; ++s) { sv[t][s] = tv[s]; si[t][s] = ti[s]; }
        }
        __syncthreads();
    }

    // exact rescore of the 16 candidates: score = 2*dot(xt_b, xtr_n) - rowsum_n (fp64)
    const int w = t >> 6, lane = t & 63;
    for (int c = w; c < GTOP; c += 4) {
        int n = si[0][c];
        double dot = 0.0, rs = 0.0;
        if (n < N_TRAIN) {
            const float4* pa = (const float4*)(xt + (size_t)b * D_DIM);
            const float4* pb = (const float4*)(xtr + (size_t)n * D_DIM);
            for (int j = lane; j < 196; j += 64) {    // 196 float4 = 784 dims
                float4 a = pa[j], bb = pb[j];
                dot += (double)a.x * bb.x + (double)a.y * bb.y +
                       (double)a.z * bb.z + (double)a.w * bb.w;
                rs  += (double)bb.x + (double)bb.y + (double)bb.z + (double)bb.w;
            }
        }
        #pragma unroll
        for (int off = 32; off > 0; off >>= 1) {
            dot += __shfl_down(dot, off, 64);
            rs  += __shfl_down(rs, off, 64);
        }
        if (lane == 0) {
            cs[c] = (n < N_TRAIN) ? (2.0 * dot - rs) : -1.0e300;
            cn[c] = n;
        }
    }
    __syncthreads();

    if (t == 0) {
        double bv[TOPK]; int bi[TOPK];
        #pragma unroll
        for (int s = 0; s < TOPK; ++s) { bv[s] = -1.0e300; bi[s] = 0x7fffffff; }
        for (int c = 0; c < GTOP; ++c) {
            double cv = cs[c]; int ci = cn[c];
            #pragma unroll
            for (int s = 0; s < TOPK; ++s) {
                bool bet = (cv > bv[s]) || (cv == bv[s] && ci < bi[s]);
                double fv = bet ? bv[s] : cv;
                int    fi = bet ? bi[s] : ci;
                bv[s] = bet ? cv : bv[s];
                bi[s] = bet ? ci : bi[s];
                cv = fv; ci = fi;
            }
        }
        int lab[TOPK];
        #pragma unroll
        for (int s = 0; s < TOPK; ++s) lab[s] = y[bi[s]];
        int best_c = 0, best_cnt = -1;
        #pragma unroll
        for (int c = 0; c < N_CLASSES; ++c) {
            int cnt = 0;
            #pragma unroll
            for (int s = 0; s < TOPK; ++s) cnt += (lab[s] == c) ? 1 : 0;
            if (cnt > best_cnt) { best_cnt = cnt; best_c = c; }
        }
        out[b] = best_c;
    }
}

// ================= fallback (round-1 fp32 path, known-correct) =================
#define FBM 64
#define FBN 64
#define FBK 16
#define FNCH 32
#define FCHUNK 1600

__global__ __launch_bounds__(256)
void knn_phaseA_fb(const float* __restrict__ xt, const float* __restrict__ xtr,
                   const float* __restrict__ strain,
                   float* __restrict__ cval, int* __restrict__ cidx) {
    __shared__ float As[FBK][FBM + 4];
    __shared__ float Bs[FBK][FBN + 4];
    __shared__ float lv[FBM][16][TOPK];
    __shared__ int   li[FBM][16][TOPK];

    const int tid = threadIdx.x;
    const int tx = tid & 15, ty = tid >> 4;
    const int b0 = blockIdx.x * FBM;
    const int chunk = blockIdx.y;
    const int n_base = chunk * FCHUNK;
    const int lrow = tid >> 2;
    const int lk4  = (tid & 3) * 4;

    float tv[4][TOPK]; int ti[4][TOPK];
    #pragma unroll
    for (int i = 0; i < 4; ++i)
        #pragma unroll
        for (int s = 0; s < TOPK; ++s) { tv[i][s] = -FLT_MAX; ti[i][s] = 0x7fffffff; }

    for (int nt = 0; nt < FCHUNK; nt += FBN) {
        const int n0 = n_base + nt;
        double accd[4][4];
        #pragma unroll
        for (int i = 0; i < 4; ++i)
            #pragma unroll
            for (int j = 0; j < 4; ++j) accd[i][j] = 0.0;

        for (int kt = 0; kt < D_DIM; kt += FBK) {
            float4 av = *(const float4*)(xt + (size_t)(b0 + lrow) * D_DIM + kt + lk4);
            As[lk4 + 0][lrow] = av.x; As[lk4 + 1][lrow] = av.y;
            As[lk4 + 2][lrow] = av.z; As[lk4 + 3][lrow] = av.w;
            int nr = n0 + lrow;
            float4 bv = make_float4(0.f, 0.f, 0.f, 0.f);
            if (nr < N_TRAIN) bv = *(const float4*)(xtr + (size_t)nr * D_DIM + kt + lk4);
            Bs[lk4 + 0][lrow] = bv.x; Bs[lk4 + 1][lrow] = bv.y;
            Bs[lk4 + 2][lrow] = bv.z; Bs[lk4 + 3][lrow] = bv.w;
            __syncthreads();

            float accf[4][4] = {{0.f}};
            #pragma unroll
            for (int k = 0; k < FBK; ++k) {
                float a[4], b[4];
                #pragma unroll
                for (int i = 0; i < 4; ++i) a[i] = As[k][ty * 4 + i];
                #pragma unroll
                for (int j = 0; j < 4; ++j) b[j] = Bs[k][tx * 4 + j];
                #pragma unroll
                for (int i = 0; i < 4; ++i)
                    #pragma unroll
                    for (int j = 0; j < 4; ++j) accf[i][j] += a[i] * b[j];
            }
            #pragma unroll
            for (int i = 0; i < 4; ++i)
                #pragma unroll
                for (int j = 0; j < 4; ++j) accd[i][j] += (double)accf[i][j];
            __syncthreads();
        }

        #pragma unroll
        for (int j = 0; j < 4; ++j) {
            int n = n0 + tx * 4 + j;
            if (n < N_TRAIN) {
                float sn = strain[n];
                #pragma unroll
                for (int i = 0; i < 4; ++i) {
                    float sc = (float)(2.0 * accd[i][j] - (double)sn);
                    if (sc > tv[i][TOPK - 1] ||
                        (sc == tv[i][TOPK - 1] && n < ti[i][TOPK - 1])) {
                        INSERT5(tv[i], ti[i], sc, n);
                    }
                }
            }
        }
    }

    #pragma unroll
    for (int i = 0; i < 4; ++i)
        #pragma unroll
        for (int s = 0; s < TOPK; ++s) {
            lv[ty * 4 + i][tx][s] = tv[i][s];
            li[ty * 4 + i][tx][s] = ti[i][s];
        }
    __syncthreads();

    if (tid < FBM) {
        float bv5[TOPK]; int bi5[TOPK];
        #pragma unroll
        for (int s = 0; s < TOPK; ++s) { bv5[s] = -FLT_MAX; bi5[s] = 0x7fffffff; }
        for (int t = 0; t < 16; ++t)
            #pragma unroll
            for (int s = 0; s < TOPK; ++s) {
                float cv = lv[tid][t][s]; int ci = li[tid][t][s];
                if (cv > bv5[TOPK - 1] || (cv == bv5[TOPK - 1] && ci < bi5[TOPK - 1])) {
                    INSERT5(bv5, bi5, cv, ci);
                }
            }
        size_t base = ((size_t)(b0 + tid) * FNCH + chunk) * TOPK;
        #pragma unroll
        for (int s = 0; s < TOPK; ++s) { cval[base + s] = bv5[s]; cidx[base + s] = bi5[s]; }
    }
}

__global__ __launch_bounds__(256)
void knn_phaseB_fb(const float* __restrict__ cval, const int* __restrict__ cidx,
                   const int* __restrict__ y, int* __restrict__ out) {
    int b = blockIdx.x * blockDim.x + threadIdx.x;
    if (b >= B_TEST) return;
    const float* v = cval + (size_t)b * FNCH * TOPK;
    const int* ix = cidx + (size_t)b * FNCH * TOPK;
    float bv5[TOPK]; int bi5[TOPK];
    #pragma unroll
    for (int s = 0; s < TOPK; ++s) { bv5[s] = -FLT_MAX; bi5[s] = 0x7fffffff; }
    for (int t = 0; t < FNCH * TOPK; ++t) {
        float cv = v[t]; int ci = ix[t];
        if (cv > bv5[TOPK - 1] || (cv == bv5[TOPK - 1] && ci < bi5[TOPK - 1])) {
            INSERT5(bv5, bi5, cv, ci);
        }
    }
    int lab[TOPK];
    #pragma unroll
    for (int s = 0; s < TOPK; ++s) lab[s] = y[bi5[s]];
    int best_c = 0, best_cnt = -1;
    #pragma unroll
    for (int c = 0; c < N_CLASSES; ++c) {
        int cnt = 0;
        #pragma unroll
        for (int s = 0; s < TOPK; ++s) cnt += (lab[s] == c) ? 1 : 0;
        if (cnt > best_cnt) { best_cnt = cnt; best_c = c; }
    }
    out[b] = best_c;
}

// =====================================================================
extern "C" void kernel_launch(void* const* d_in, const int* in_sizes, int n_in,
                              void* d_out, int out_size, void* d_ws, size_t ws_size,
                              hipStream_t stream) {
    const float* x_test  = (const float*)d_in[0];
    const float* x_train = (const float*)d_in[1];
    const int*   y_train = (const int*)d_in[2];
    int* out = (int*)d_out;

    // fast-path workspace layout (bytes)
    const size_t off_Bh = 200192;
    const size_t sz_Bh  = (size_t)NPAD * KPAD * 2;        // 83,279,872
    const size_t off_Ah = off_Bh + sz_Bh;
    const size_t sz_Ah  = (size_t)B_TEST * KPAD * 2;      // 3,407,872
    const size_t off_cv = off_Ah + sz_Ah;
    const size_t sz_cv  = (size_t)B_TEST * NBLK * TOPK * 4;  // 16,015,360
    const size_t off_ci = off_cv + sz_cv;
    const size_t need   = off_ci + sz_cv;                 // ~118.9 MB

    char* ws = (char*)d_ws;
    float* strain = (float*)ws;

    rowsum_kernel<<<N_TRAIN / 4, 256, 0, stream>>>(x_train, strain);

    if (ws_size >= need) {
        _Float16* Bh = (_Float16*)(ws + off_Bh);
        _Float16* Ah = (_Float16*)(ws + off_Ah);
        float* cval = (float*)(ws + off_cv);
        int*   cidx = (int*)(ws + off_ci);

        int tg_train = NPAD * NGRP;     // 5,204,992
        int tg_test  = B_TEST * NGRP;   // 212,992
        split_h<<<(tg_train + 255) / 256, 256, 0, stream>>>(x_train, Bh, N_TRAIN, tg_train);
        split_h<<<(tg_test + 255) / 256, 256, 0, stream>>>(x_test, Ah, B_TEST, tg_test);

        knn_mfma<<<6272, 256, 0, stream>>>(Ah, Bh, strain, cval, cidx);

        knn_final<<<B_TEST, 256, 0, stream>>>(cval, cidx, x_test, x_train, y_train, out);
    } else {
        float* cval = (float*)(ws + 200192);
        int*   cidx = (int*)(ws + 200192 + (size_t)B_TEST * FNCH * TOPK * 4);

        dim3 gridA(B_TEST / FBM, FNCH);
        knn_phaseA_fb<<<gridA, 256, 0, stream>>>(x_test, x_train, strain, cval, cidx);
        knn_phaseB_fb<<<(B_TEST + 255) / 256, 256, 0, stream>>>(cval, cidx, y_train, out);
    }
}

// Round 5
// 485.708 us; speedup vs baseline: 8.0449x; 1.8386x over previous
//
#include <hip/hip_runtime.h>
#include <float.h>
#include <stdint.h>

#define D_DIM 784
#define KPAD 832            // 13 x 64
#define N_TRAIN 50000
#define NPAD 50048
#define B_TEST 2048
#define N_CLASSES 10
#define TOPK 5
#define NBLK 391            // ceil(50048/128)
#define SEL 8               // exact-rescore candidate count per row

typedef __attribute__((ext_vector_type(8))) _Float16 half8;
typedef __attribute__((ext_vector_type(4))) float float4v;

__device__ inline unsigned umax32(unsigned a, unsigned b) { return a > b ? a : b; }

// monotonic float->u32 key, low 7 bits replaced by col
__device__ inline unsigned pack_key(float s, int col) {
    unsigned u = __float_as_uint(s);
    unsigned mask = (unsigned)((int)u >> 31) | 0x80000000u;
    unsigned k = u ^ mask;
    return (k & 0xFFFFFF80u) | (unsigned)col;
}

// branchless sorted-insert (desc) of u64 into 8-deep list
__device__ inline void ins8(unsigned long long* tk, unsigned long long v) {
    #pragma unroll
    for (int s = 0; s < SEL; ++s) {
        unsigned long long mx = v > tk[s] ? v : tk[s];
        unsigned long long mn = v > tk[s] ? tk[s] : v;
        tk[s] = mx; v = mn;
    }
}

// branchless sorted-insert (desc) of u32 into 5-deep list
__device__ inline void ins5u(unsigned* tk, unsigned v) {
    #pragma unroll
    for (int s = 0; s < TOPK; ++s) {
        unsigned mx = v > tk[s] ? v : tk[s];
        unsigned mn = v > tk[s] ? tk[s] : v;
        tk[s] = mx; v = mn;
    }
}

// float pair-insert for fallback path
#define INSERT5(tvarr, tiarr, CV, CI)                                   \
    {                                                                   \
        float _cv = (CV); int _ci = (CI);                               \
        _Pragma("unroll")                                               \
        for (int _s = 0; _s < TOPK; ++_s) {                             \
            bool _bet = (_cv > tvarr[_s]) ||                            \
                        (_cv == tvarr[_s] && _ci < tiarr[_s]);          \
            float _fv = _bet ? tvarr[_s] : _cv;                         \
            int   _fi = _bet ? tiarr[_s] : _ci;                         \
            tvarr[_s] = _bet ? _cv : tvarr[_s];                         \
            tiarr[_s] = _bet ? _ci : tiarr[_s];                         \
            _cv = _fv; _ci = _fi;                                       \
        }                                                               \
    }

// ------------- fused split fp32->f16 + rowsum (one wave per row) -------------
__global__ __launch_bounds__(256)
void split_rowsum(const float* __restrict__ src, _Float16* __restrict__ hi,
                  float* __restrict__ strain, int rows_src, int rows_pad, int do_sum) {
    int row = blockIdx.x * 4 + (threadIdx.x >> 6);
    int lane = threadIdx.x & 63;
    if (row >= rows_pad) return;
    const float* p = src + (size_t)row * D_DIM;
    float sum = 0.f;

    // group 0: g = lane (0..63, all real)
    {
        float v[8];
        if (row < rows_src) {
            float4 a = *(const float4*)(p + lane * 8);
            float4 b = *(const float4*)(p + lane * 8 + 4);
            v[0]=a.x; v[1]=a.y; v[2]=a.z; v[3]=a.w; v[4]=b.x; v[5]=b.y; v[6]=b.z; v[7]=b.w;
        } else {
            #pragma unroll
            for (int i = 0; i < 8; ++i) v[i] = 0.f;
        }
        half8 h8;
        #pragma unroll
        for (int i = 0; i < 8; ++i) { h8[i] = (_Float16)v[i]; sum += v[i]; }
        *(half8*)(hi + (size_t)row * KPAD + lane * 8) = h8;
    }
    // group 1: g = 64+lane (lanes 0..39; real data for g<98 i.e. lanes 0..33)
    if (lane < 40) {
        int g = 64 + lane;
        float v[8];
        if (row < rows_src && g < 98) {
            float4 a = *(const float4*)(p + g * 8);
            float4 b = *(const float4*)(p + g * 8 + 4);
            v[0]=a.x; v[1]=a.y; v[2]=a.z; v[3]=a.w; v[4]=b.x; v[5]=b.y; v[6]=b.z; v[7]=b.w;
        } else {
            #pragma unroll
            for (int i = 0; i < 8; ++i) v[i] = 0.f;
        }
        half8 h8;
        #pragma unroll
        for (int i = 0; i < 8; ++i) { h8[i] = (_Float16)v[i]; sum += v[i]; }
        *(half8*)(hi + (size_t)row * KPAD + g * 8) = h8;
    }
    #pragma unroll
    for (int off = 32; off > 0; off >>= 1) sum += __shfl_down(sum, off, 64);
    if (lane == 0 && do_sum) strain[row] = sum;
}

// ---------------- 1-term f16 MFMA GEMM + packed-u32 top-5 epilogue ----------------
__global__ __launch_bounds__(256, 3)
void knn_mfma(const _Float16* __restrict__ Ah, const _Float16* __restrict__ Bh,
              const float* __restrict__ strain, unsigned* __restrict__ cval) {
    const int bid = blockIdx.x;
    const int xcd = bid & 7;
    const int sidx = bid >> 3;
    const int st_g = (sidx >> 4) * 8 + xcd;
    const int r16 = sidx & 15;
    const int mblk = (st_g & 3) * 4 + (r16 & 3);
    const int nchunk = (st_g >> 2) * 4 + (r16 >> 2);
    if (nchunk >= NBLK) return;

    __shared__ char lds_raw[39936] __attribute__((aligned(16)));
    _Float16* stage = (_Float16*)lds_raw;            // 2 tiles x 16 KB
    unsigned* epi  = (unsigned*)lds_raw;             // [128 cols][68] u32
    unsigned* lval = (unsigned*)(lds_raw + 34816);   // [64][4][5] u32

    const int tid = threadIdx.x;
    const int w = tid >> 6, lane = tid & 63;
    const int l15 = lane & 15, q = lane >> 4;
    const int mb = mblk * 128, nb = nchunk * 128;
    const int mw = (w & 1) * 64, nw = (w >> 1) * 64;

    // staging: wave w loads half-tile: tile = w>>1 (0=A,1=B), half = w&1
    const int s_tile = w >> 1, s_half = w & 1;
    const _Float16* sbase = (s_tile == 0) ? (Ah + (size_t)mb * KPAD)
                                          : (Bh + (size_t)nb * KPAD);
    const _Float16* srow = sbase + (size_t)s_half * 64 * KPAD;
    _Float16* ldsw = stage + s_tile * 8192 + s_half * 4096;   // halves

    int choff[8];
    #pragma unroll
    for (int c = 0; c < 8; ++c) {
        int s = c * 64 + lane;
        int rl = s >> 3;
        int k8 = (s & 7) ^ (rl & 7);
        choff[c] = rl * KPAD + k8 * 8;
    }
    int aoff[4][2], boff[4][2];
    #pragma unroll
    for (int i = 0; i < 4; ++i)
        #pragma unroll
        for (int k32 = 0; k32 < 2; ++k32) {
            int r = mw + i * 16 + l15;
            aoff[i][k32] = (r * 8 + ((k32 * 4 + q) ^ (r & 7))) * 8;
            r = nw + i * 16 + l15;
            boff[i][k32] = (r * 8 + ((k32 * 4 + q) ^ (r & 7))) * 8;
        }

    float4v acc[4][4];
    #pragma unroll
    for (int i = 0; i < 4; ++i)
        #pragma unroll
        for (int j = 0; j < 4; ++j)
            acc[i][j] = (float4v){0.f, 0.f, 0.f, 0.f};

    for (int kt = 0; kt < KPAD; kt += 64) {
        #pragma unroll
        for (int c = 0; c < 8; ++c) {
            __builtin_amdgcn_global_load_lds(
                (const __attribute__((address_space(1))) void*)(srow + choff[c] + kt),
                (__attribute__((address_space(3))) void*)(ldsw + c * 512),
                16, 0, 0);
        }
        __syncthreads();
        #pragma unroll
        for (int k32 = 0; k32 < 2; ++k32) {
            half8 a[4], b[4];
            #pragma unroll
            for (int i = 0; i < 4; ++i) a[i] = *(const half8*)(stage + aoff[i][k32]);
            #pragma unroll
            for (int j = 0; j < 4; ++j) b[j] = *(const half8*)(stage + 8192 + boff[j][k32]);
            #pragma unroll
            for (int i = 0; i < 4; ++i)
                #pragma unroll
                for (int j = 0; j < 4; ++j)
                    acc[i][j] = __builtin_amdgcn_mfma_f32_16x16x32_f16(a[i], b[j], acc[i][j], 0, 0, 0);
        }
        __syncthreads();
    }

    // ---- epilogue: packed keys + branch-free top-5 per (row, chunk) ----
    float st[4]; int okn[4];
    #pragma unroll
    for (int j = 0; j < 4; ++j) {
        int n = nb + nw + j * 16 + l15;
        okn[j] = (n < N_TRAIN);
        st[j] = okn[j] ? strain[n] : 0.f;
    }

    for (int h = 0; h < 2; ++h) {
        __syncthreads();
        if ((w & 1) == h) {
            #pragma unroll
            for (int i = 0; i < 4; ++i) {
                int r = i * 16 + q * 4;
                #pragma unroll
                for (int j = 0; j < 4; ++j) {
                    int col = nw + j * 16 + l15;
                    uint4 kv;
                    if (okn[j]) {
                        float4v v = acc[i][j] * 2.0f;
                        v = v - st[j];
                        kv.x = pack_key(v.x, col);
                        kv.y = pack_key(v.y, col);
                        kv.z = pack_key(v.z, col);
                        kv.w = pack_key(v.w, col);
                    } else {
                        kv.x = kv.y = kv.z = kv.w = (unsigned)col;
                    }
                    *(uint4*)(epi + col * 68 + r) = kv;
                }
            }
        }
        __syncthreads();
        // scan: thread t -> row (t&63), col-quarter (t>>6); branch-free extraction
        {
            int r = tid & 63, qq = tid >> 6;
            const unsigned* ebase = epi + (qq * 32) * 68 + r;
            unsigned k[32];
            #pragma unroll
            for (int c = 0; c < 32; ++c) k[c] = ebase[c * 68];
            unsigned m5[TOPK];
            #pragma unroll
            for (int rnd = 0; rnd < TOPK; ++rnd) {
                unsigned t16[16];
                #pragma unroll
                for (int c = 0; c < 16; ++c) t16[c] = umax32(k[2*c], k[2*c+1]);
                #pragma unroll
                for (int c = 0; c < 8; ++c) t16[c] = umax32(t16[2*c], t16[2*c+1]);
                #pragma unroll
                for (int c = 0; c < 4; ++c) t16[c] = umax32(t16[2*c], t16[2*c+1]);
                unsigned m = umax32(umax32(t16[0], t16[1]), umax32(t16[2], t16[3]));
                m5[rnd] = m;
                if (rnd < TOPK - 1) {
                    #pragma unroll
                    for (int c = 0; c < 32; ++c) k[c] = (k[c] == m) ? 0u : k[c];
                }
            }
            #pragma unroll
            for (int s = 0; s < TOPK; ++s) lval[(r * 4 + qq) * TOPK + s] = m5[s];
        }
        __syncthreads();
        if (tid < 64) {
            unsigned tv[TOPK] = {0u, 0u, 0u, 0u, 0u};
            for (int qq = 0; qq < 4; ++qq)
                #pragma unroll
                for (int s = 0; s < TOPK; ++s) {
                    unsigned cv = lval[(tid * 4 + qq) * TOPK + s];
                    if (cv > tv[TOPK - 1]) ins5u(tv, cv);
                }
            int grow = mb + h * 64 + tid;
            size_t base = ((size_t)grow * NBLK + nchunk) * TOPK;
            #pragma unroll
            for (int s = 0; s < TOPK; ++s) cval[base + s] = tv[s];
        }
    }
}

// ------- merge packed candidates -> top-8, exact fp64 rescore, vote -------
__global__ __launch_bounds__(256)
void knn_final(const unsigned* __restrict__ cval,
               const float* __restrict__ xt, const float* __restrict__ xtr,
               const int* __restrict__ y, int* __restrict__ out) {
    __shared__ unsigned long long sv[256][SEL];   // 16 KB
    __shared__ double cs[SEL];
    __shared__ int    cn[SEL];
    const int b = blockIdx.x;
    const int t = threadIdx.x;

    unsigned long long tk[SEL];
    #pragma unroll
    for (int s = 0; s < SEL; ++s) tk[s] = 0ull;

    const unsigned* row = cval + (size_t)b * (NBLK * TOPK);
    for (int e = t; e < NBLK * TOPK; e += 256) {
        unsigned v = row[e];
        int chunk = e / TOPK;                       // magic-mul
        unsigned n = (unsigned)chunk * 128u + (v & 127u);
        unsigned long long v64 = ((unsigned long long)v << 16) | n;
        if (v64 > tk[SEL - 1]) ins8(tk, v64);
    }
    #pragma unroll
    for (int s = 0; s < SEL; ++s) sv[t][s] = tk[s];
    __syncthreads();

    for (int off = 128; off >= 1; off >>= 1) {
        if (t < off) {
            if (sv[t + off][0] > tk[SEL - 1]) {
                #pragma unroll
                for (int s = 0; s < SEL; ++s) {
                    unsigned long long v = sv[t + off][s];
                    if (v > tk[SEL - 1]) ins8(tk, v);
                }
                #pragma unroll
                for (int s = 0; s < SEL; ++s) sv[t][s] = tk[s];
            }
        }
        __syncthreads();
    }

    // exact fp64 rescore: candidate c handled by half-wave (w*2 + half)
    const int w = t >> 6, lane = t & 63, half = lane >> 5, hl = lane & 31;
    const int c = w * 2 + half;
    {
        int n = (int)(sv[0][c] & 0xFFFFull);
        double dot = 0.0, rs = 0.0;
        if (n < N_TRAIN) {
            const float4* pa = (const float4*)(xt + (size_t)b * D_DIM);
            const float4* pb = (const float4*)(xtr + (size_t)n * D_DIM);
            #pragma unroll
            for (int jj = 0; jj < 7; ++jj) {
                int j = hl + jj * 32;
                if (j < 196) {
                    float4 a = pa[j], bb = pb[j];
                    dot += (double)a.x * bb.x + (double)a.y * bb.y +
                           (double)a.z * bb.z + (double)a.w * bb.w;
                    rs  += (double)bb.x + (double)bb.y + (double)bb.z + (double)bb.w;
                }
            }
        }
        #pragma unroll
        for (int off = 16; off > 0; off >>= 1) {
            dot += __shfl_down(dot, off, 32);
            rs  += __shfl_down(rs, off, 32);
        }
        if (hl == 0) {
            cs[c] = (n < N_TRAIN) ? (2.0 * dot - rs) : -1.0e300;
            cn[c] = n;
        }
    }
    __syncthreads();

    if (t == 0) {
        double bv[TOPK]; int bi[TOPK];
        #pragma unroll
        for (int s = 0; s < TOPK; ++s) { bv[s] = -1.0e300; bi[s] = 0x7fffffff; }
        for (int cc = 0; cc < SEL; ++cc) {
            double cv = cs[cc]; int ci = cn[cc];
            #pragma unroll
            for (int s = 0; s < TOPK; ++s) {
                bool bet = (cv > bv[s]) || (cv == bv[s] && ci < bi[s]);
                double fv = bet ? bv[s] : cv;
                int    fi = bet ? bi[s] : ci;
                bv[s] = bet ? cv : bv[s];
                bi[s] = bet ? ci : bi[s];
                cv = fv; ci = fi;
            }
        }
        int lab[TOPK];
        #pragma unroll
        for (int s = 0; s < TOPK; ++s) lab[s] = y[bi[s]];
        int best_c = 0, best_cnt = -1;
        #pragma unroll
        for (int cc = 0; cc < N_CLASSES; ++cc) {
            int cnt = 0;
            #pragma unroll
            for (int s = 0; s < TOPK; ++s) cnt += (lab[s] == cc) ? 1 : 0;
            if (cnt > best_cnt) { best_cnt = cnt; best_c = cc; }
        }
        out[b] = best_c;
    }
}

// ================= fallback (round-1 fp32 path, known-correct) =================
#define FBM 64
#define FBN 64
#define FBK 16
#define FNCH 32
#define FCHUNK 1600

__global__ __launch_bounds__(256)
void rowsum_kernel(const float* __restrict__ x, float* __restrict__ s) {
    int row = blockIdx.x * 4 + (threadIdx.x >> 6);
    int lane = threadIdx.x & 63;
    if (row >= N_TRAIN) return;
    const float* p = x + (size_t)row * D_DIM;
    float acc = 0.f;
    for (int i = lane; i < D_DIM; i += 64) acc += p[i];
    #pragma unroll
    for (int off = 32; off > 0; off >>= 1) acc += __shfl_down(acc, off, 64);
    if (lane == 0) s[row] = acc;
}

__global__ __launch_bounds__(256)
void knn_phaseA_fb(const float* __restrict__ xt, const float* __restrict__ xtr,
                   const float* __restrict__ strain,
                   float* __restrict__ cval, int* __restrict__ cidx) {
    __shared__ float As[FBK][FBM + 4];
    __shared__ float Bs[FBK][FBN + 4];
    __shared__ float lv[FBM][16][TOPK];
    __shared__ int   li[FBM][16][TOPK];

    const int tid = threadIdx.x;
    const int tx = tid & 15, ty = tid >> 4;
    const int b0 = blockIdx.x * FBM;
    const int chunk = blockIdx.y;
    const int n_base = chunk * FCHUNK;
    const int lrow = tid >> 2;
    const int lk4  = (tid & 3) * 4;

    float tv[4][TOPK]; int ti[4][TOPK];
    #pragma unroll
    for (int i = 0; i < 4; ++i)
        #pragma unroll
        for (int s = 0; s < TOPK; ++s) { tv[i][s] = -FLT_MAX; ti[i][s] = 0x7fffffff; }

    for (int nt = 0; nt < FCHUNK; nt += FBN) {
        const int n0 = n_base + nt;
        double accd[4][4];
        #pragma unroll
        for (int i = 0; i < 4; ++i)
            #pragma unroll
            for (int j = 0; j < 4; ++j) accd[i][j] = 0.0;

        for (int kt = 0; kt < D_DIM; kt += FBK) {
            float4 av = *(const float4*)(xt + (size_t)(b0 + lrow) * D_DIM + kt + lk4);
            As[lk4 + 0][lrow] = av.x; As[lk4 + 1][lrow] = av.y;
            As[lk4 + 2][lrow] = av.z; As[lk4 + 3][lrow] = av.w;
            int nr = n0 + lrow;
            float4 bv = make_float4(0.f, 0.f, 0.f, 0.f);
            if (nr < N_TRAIN) bv = *(const float4*)(xtr + (size_t)nr * D_DIM + kt + lk4);
            Bs[lk4 + 0][lrow] = bv.x; Bs[lk4 + 1][lrow] = bv.y;
            Bs[lk4 + 2][lrow] = bv.z; Bs[lk4 + 3][lrow] = bv.w;
            __syncthreads();

            float accf[4][4] = {{0.f}};
            #pragma unroll
            for (int k = 0; k < FBK; ++k) {
                float a[4], b[4];
                #pragma unroll
                for (int i = 0; i < 4; ++i) a[i] = As[k][ty * 4 + i];
                #pragma unroll
                for (int j = 0; j < 4; ++j) b[j] = Bs[k][tx * 4 + j];
                #pragma unroll
                for (int i = 0; i < 4; ++i)
                    #pragma unroll
                    for (int j = 0; j < 4; ++j) accf[i][j] += a[i] * b[j];
            }
            #pragma unroll
            for (int i = 0; i < 4; ++i)
                #pragma unroll
                for (int j = 0; j < 4; ++j) accd[i][j] += (double)accf[i][j];
            __syncthreads();
        }

        #pragma unroll
        for (int j = 0; j < 4; ++j) {
            int n = n0 + tx * 4 + j;
            if (n < N_TRAIN) {
                float sn = strain[n];
                #pragma unroll
                for (int i = 0; i < 4; ++i) {
                    float sc = (float)(2.0 * accd[i][j] - (double)sn);
                    if (sc > tv[i][TOPK - 1] ||
                        (sc == tv[i][TOPK - 1] && n < ti[i][TOPK - 1])) {
                        INSERT5(tv[i], ti[i], sc, n);
                    }
                }
            }
        }
    }

    #pragma unroll
    for (int i = 0; i < 4; ++i)
        #pragma unroll
        for (int s = 0; s < TOPK; ++s) {
            lv[ty * 4 + i][tx][s] = tv[i][s];
            li[ty * 4 + i][tx][s] = ti[i][s];
        }
    __syncthreads();

    if (tid < FBM) {
        float bv5[TOPK]; int bi5[TOPK];
        #pragma unroll
        for (int s = 0; s < TOPK; ++s) { bv5[s] = -FLT_MAX; bi5[s] = 0x7fffffff; }
        for (int tt = 0; tt < 16; ++tt)
            #pragma unroll
            for (int s = 0; s < TOPK; ++s) {
                float cv = lv[tid][tt][s]; int ci = li[tid][tt][s];
                if (cv > bv5[TOPK - 1] || (cv == bv5[TOPK - 1] && ci < bi5[TOPK - 1])) {
                    INSERT5(bv5, bi5, cv, ci);
                }
            }
        size_t base = ((size_t)(b0 + tid) * FNCH + chunk) * TOPK;
        #pragma unroll
        for (int s = 0; s < TOPK; ++s) { cval[base + s] = bv5[s]; cidx[base + s] = bi5[s]; }
    }
}

__global__ __launch_bounds__(256)
void knn_phaseB_fb(const float* __restrict__ cval, const int* __restrict__ cidx,
                   const int* __restrict__ y, int* __restrict__ out) {
    int b = blockIdx.x * blockDim.x + threadIdx.x;
    if (b >= B_TEST) return;
    const float* v = cval + (size_t)b * FNCH * TOPK;
    const int* ix = cidx + (size_t)b * FNCH * TOPK;
    float bv5[TOPK]; int bi5[TOPK];
    #pragma unroll
    for (int s = 0; s < TOPK; ++s) { bv5[s] = -FLT_MAX; bi5[s] = 0x7fffffff; }
    for (int tt = 0; tt < FNCH * TOPK; ++tt) {
        float cv = v[tt]; int ci = ix[tt];
        if (cv > bv5[TOPK - 1] || (cv == bv5[TOPK - 1] && ci < bi5[TOPK - 1])) {
            INSERT5(bv5, bi5, cv, ci);
        }
    }
    int lab[TOPK];
    #pragma unroll
    for (int s = 0; s < TOPK; ++s) lab[s] = y[bi5[s]];
    int best_c = 0, best_cnt = -1;
    #pragma unroll
    for (int cc = 0; cc < N_CLASSES; ++cc) {
        int cnt = 0;
        #pragma unroll
        for (int s = 0; s < TOPK; ++s) cnt += (lab[s] == cc) ? 1 : 0;
        if (cnt > best_cnt) { best_cnt = cnt; best_c = cc; }
    }
    out[b] = best_c;
}

// =====================================================================
extern "C" void kernel_launch(void* const* d_in, const int* in_sizes, int n_in,
                              void* d_out, int out_size, void* d_ws, size_t ws_size,
                              hipStream_t stream) {
    const float* x_test  = (const float*)d_in[0];
    const float* x_train = (const float*)d_in[1];
    const int*   y_train = (const int*)d_in[2];
    int* out = (int*)d_out;

    // fast-path workspace layout (bytes)
    const size_t off_Bh = 200192;                          // strain: NPAD floats
    const size_t sz_Bh  = (size_t)NPAD * KPAD * 2;         // 83,279,872
    const size_t off_Ah = off_Bh + sz_Bh;
    const size_t sz_Ah  = (size_t)B_TEST * KPAD * 2;       // 3,407,872
    const size_t off_cv = off_Ah + sz_Ah;
    const size_t sz_cv  = (size_t)B_TEST * NBLK * TOPK * 4;  // 16,015,360
    const size_t need   = off_cv + sz_cv;                  // ~102.9 MB

    char* ws = (char*)d_ws;
    float* strain = (float*)ws;

    if (ws_size >= need) {
        _Float16* Bh = (_Float16*)(ws + off_Bh);
        _Float16* Ah = (_Float16*)(ws + off_Ah);
        unsigned* cval = (unsigned*)(ws + off_cv);

        split_rowsum<<<NPAD / 4, 256, 0, stream>>>(x_train, Bh, strain, N_TRAIN, NPAD, 1);
        split_rowsum<<<B_TEST / 4, 256, 0, stream>>>(x_test, Ah, strain, B_TEST, B_TEST, 0);

        knn_mfma<<<6272, 256, 0, stream>>>(Ah, Bh, strain, cval);

        knn_final<<<B_TEST, 256, 0, stream>>>(cval, x_test, x_train, y_train, out);
    } else {
        rowsum_kernel<<<N_TRAIN / 4, 256, 0, stream>>>(x_train, strain);
        float* cval = (float*)(ws + 200192);
        int*   cidx = (int*)(ws + 200192 + (size_t)B_TEST * FNCH * TOPK * 4);

        dim3 gridA(B_TEST / FBM, FNCH);
        knn_phaseA_fb<<<gridA, 256, 0, stream>>>(x_test, x_train, strain, cval, cidx);
        knn_phaseB_fb<<<(B_TEST + 255) / 256, 256, 0, stream>>>(cval, cidx, y_train, out);
    }
}